// Round 9
// baseline (8581.181 us; speedup 1.0000x reference)
//
#include <hip/hip_runtime.h>
#include <math.h>

#define HID   512
#define SEQL  256
#define BATCH 2048
#define NCLS  10
#define NB    16     // batch columns per WG = full MFMA tile width
#define H8S   544    // bytes per fp8 h row in LDS (512 used; 16B-mult)

typedef _Float16 f16x8 __attribute__((ext_vector_type(8)));
typedef _Float16 f16x4 __attribute__((ext_vector_type(4)));
typedef _Float16 f16x2 __attribute__((ext_vector_type(2)));
typedef float    f32x4 __attribute__((ext_vector_type(4)));
typedef int      i32x4 __attribute__((ext_vector_type(4)));
typedef int      i32x8 __attribute__((ext_vector_type(8)));
typedef long     i64;
typedef long     i64x2 __attribute__((ext_vector_type(2)));

__device__ __forceinline__ float fsig(float v)  { return 1.f / (1.f + __expf(-v)); }
__device__ __forceinline__ float ftanh(float v) { return 1.f - 2.f / (1.f + __expf(2.f * v)); }

// e2m1 nearest-round quantize of y (pre-scaled); grid {0,.5,1,1.5,2,3,4,6}.
__device__ __forceinline__ unsigned q4(float y) {
    const unsigned s = (y < 0.f) ? 8u : 0u;
    const float a = fabsf(y);
    const unsigned c = a < 0.25f ? 0u : a < 0.75f ? 1u : a < 1.25f ? 2u :
                       a < 1.75f ? 3u : a < 2.5f  ? 4u : a < 3.5f  ? 5u :
                       a < 5.0f  ? 6u : 7u;
    return s | c;
}

// ---- g-gate: fp8 chunk-pair fragments (EXACT R7 machinery, 1 gate) -------
// wqg[(((wv*4+sc)*4+pi)*2+h)*64 + lane] : uint4 = A-frags for row-tile
// p = wv+8*pi, K=32 subchunks m0=4sc+2h (bytes 0-7), m1=m0+1 (bytes 8-15).
// byte v: fp8( wg[16p+(l&15)][(4sc+2h+(v>>3))*32 + (l>>4)*8 + (v&7)] * 128 ).
__global__ void pack_g(const float* __restrict__ wg, uint4* __restrict__ wqg)
{
    const int idx = blockIdx.x * 256 + threadIdx.x;   // 16384
    const int lane = idx & 63;
    const int h  = (idx >> 6) & 1;
    const int pi = (idx >> 7) & 3;
    const int sc = (idx >> 9) & 3;
    const int wv = idx >> 11;
    const int j = 16 * (wv + 8 * pi) + (lane & 15);
    unsigned dw[4];
    #pragma unroll
    for (int d = 0; d < 4; d++) {
        float f[4];
        #pragma unroll
        for (int e = 0; e < 4; e++) {
            const int v = 4 * d + e;
            const int k = (4 * sc + 2 * h + (v >> 3)) * 32 + (lane >> 4) * 8 + (v & 7);
            f[e] = wg[j * HID + k] * 128.f;
        }
        int pk = __builtin_amdgcn_cvt_pk_fp8_f32(f[0], f[1], 0, false);
        pk     = __builtin_amdgcn_cvt_pk_fp8_f32(f[2], f[3], pk, true);
        dw[d] = (unsigned)pk;
    }
    wqg[idx] = make_uint4(dw[0], dw[1], dw[2], dw[3]);
}

// ---- i/f/o: fp4 K=128 fragments (EXACT R8 machinery, 3 gates) ------------
// wq4[((wv*4+sc)*12 + t12)*64 + lane], t12 = gt*4+pi (gt: 0=i,1=f,2=o):
// lane l holds 32 nibbles, element v: k = 128sc + (l>>4)*32 + v,
// row j = 16(wv+8pi)+(l&15); fp4(w * 1024).
__global__ void pack_ifo(const float* __restrict__ wi, const float* __restrict__ wf,
                         const float* __restrict__ wo, i32x4* __restrict__ wq4)
{
    const int idx = blockIdx.x * 256 + threadIdx.x;   // 24576
    const int lane = idx & 63, blk = idx >> 6;
    const int t12 = blk % 12, r = blk / 12;
    const int sc = r & 3, wv = r >> 2;
    const int gt = t12 >> 2, pi = t12 & 3;
    const int j = 16 * (wv + 8 * pi) + (lane & 15);
    const int kbase = 128 * sc + (lane >> 4) * 32;
    const float* w = (gt == 0) ? wi : (gt == 1) ? wf : wo;
    int dw[4];
    #pragma unroll
    for (int d = 0; d < 4; d++) {
        unsigned u = 0;
        #pragma unroll
        for (int by = 0; by < 4; by++) {
            const int e0 = 8 * d + 2 * by;
            const unsigned c0 = q4(w[j * HID + kbase + e0]     * 1024.f);
            const unsigned c1 = q4(w[j * HID + kbase + e0 + 1] * 1024.f);
            u |= (c0 | (c1 << 4)) << (8 * by);
        }
        dw[d] = (int)u;
    }
    wq4[idx] = (i32x4){dw[0], dw[1], dw[2], dw[3]};
}

__device__ __forceinline__ f32x4 mma8(i64 a, i64 b, f32x4 c) {
    return __builtin_amdgcn_mfma_f32_16x16x32_fp8_fp8(a, b, c, 0, 0, 0);
}
// A fp4 (cbsz=4), B fp8 (blgp=0), neutral E8M0 scales.
__device__ __forceinline__ f32x4 mma4(i32x4 a, i32x8 b, f32x4 c) {
    const i32x8 av = __builtin_shufflevector(a, (i32x4){0, 0, 0, 0},
                                             0, 1, 2, 3, 4, 5, 6, 7);
    return __builtin_amdgcn_mfma_scale_f32_16x16x128_f8f6f4(
        av, b, c, 4, 0, 0, 0x7F7F7F7F, 0, 0x7F7F7F7F);
}
__device__ __forceinline__ i32x8 ld_b32(const char* p) {
    const i32x4 a = *(const i32x4*)p;
    const i32x4 b = *(const i32x4*)(p + 16);
    return __builtin_shufflevector(a, b, 0, 1, 2, 3, 4, 5, 6, 7);
}

// Persistent mixed-precision MFMA LSTM. 128 WGs x 512 thr (8 waves/CU).
// R8 post-mortem: g-gate preact noise reaches h with gain ~0.9; i/f/o with
// gain ~0.001 -> g must stay fp8 (R7-proven invisible), ifo can be fp4.
// VMEM: 32 (g, fp8 pairs) + 48 (ifo, fp4 K=128) = 80 loads/wave/step
// (R7: 128). Scales: g acc = preact*2^14 (w*128, h*128); ifo acc =
// preact*2^17 (w*1024, h*128). Bias in f16 regs, added post-unscale.
__global__ __launch_bounds__(512, 1) void lstm_mfma(
    const float* __restrict__ x,                                   // [B][SEQ]
    const uint4* __restrict__ wqg, const i32x4* __restrict__ wq4,  // packed w
    const float* __restrict__ wgx, const float* __restrict__ wix,
    const float* __restrict__ wfx, const float* __restrict__ wox,  // [H]
    const float* __restrict__ bg,  const float* __restrict__ bi,
    const float* __restrict__ bf_, const float* __restrict__ bo,   // [H]
    const float* __restrict__ wph, const float* __restrict__ bp,   // [C][H], [C]
    const float* __restrict__ h_init, const float* __restrict__ c_init, // [H]
    float* __restrict__ out)                                       // [B][C]
{
    __shared__ __align__(16) char     h8s[2][NB * H8S];   // 17 KB fp8 h (x128)
    __shared__ float x_s[NB][SEQL + 1];                   // 16.4 KB
    __shared__ __align__(16) _Float16 hfin[NB][HID];      // 16 KB (final h only)

    const int tid  = threadIdx.x;
    const int lane = tid & 63;
    const int wv   = tid >> 6;
    const int col  = lane & 15;
    const int kq   = lane >> 4;
    const int b0   = blockIdx.x * NB;
    const int gbase = wv * 2048 + lane;   // uint4 units
    const int qbase = wv * 3072 + lane;   // i32x4 units

    for (int i = tid; i < NB * SEQL; i += 512)
        x_s[i >> 8][i & 255] = x[(b0 + (i >> 8)) * SEQL + (i & 255)];

    for (int i = tid; i < 2 * NB * H8S; i += 512) {
        const int b = i / (NB * H8S), k = (i % (NB * H8S)) % H8S;
        const float v = (b == 0 && k < HID) ? h_init[k] * 128.f : 0.f;
        const int pk = __builtin_amdgcn_cvt_pk_fp8_f32(v, 0.f, 0, false);
        ((char*)h8s)[i] = (char)(pk & 0xff);
    }

    const int j00 = 16 * wv + 4 * kq;     // + 128*pi per tile row-block
    f32x4 creg[4];
    #pragma unroll
    for (int pi = 0; pi < 4; pi++) creg[pi] = *(const f32x4*)&c_init[j00 + 128 * pi];

    // Seed A values: acc idx a: 0-3 = g(pi), 4+t12 = ifo. f16(wx * gate scale).
    unsigned sv2[8];
    {
        const float* gxp[4] = {wgx, wix, wfx, wox};
        #pragma unroll
        for (int a2 = 0; a2 < 8; a2++) {
            f16x2 pr;
            #pragma unroll
            for (int half = 0; half < 2; half++) {
                const int a  = 2 * a2 + half;
                const int pi = (a < 4) ? a : ((a - 4) & 3);
                const int gs = (a < 4) ? 0 : 1 + ((a - 4) >> 2);
                const float wx = gxp[gs][16 * (wv + 8 * pi) + col];
                const float sc = (a < 4) ? 16384.f : 131072.f;
                pr[half] = (_Float16)(wx * sc);
            }
            sv2[a2] = (kq == 0) ? __builtin_bit_cast(unsigned, pr) : 0u;
        }
    }
    // Bias, f16x4 per acc tile (rows j00+128pi .. +3).
    f16x4 bjv[16];
    {
        const float* bpt[4] = {bg, bi, bf_, bo};
        #pragma unroll
        for (int a = 0; a < 16; a++) {
            const int pi = (a < 4) ? a : ((a - 4) & 3);
            const int gs = (a < 4) ? 0 : 1 + ((a - 4) >> 2);
            const int j0 = j00 + 128 * pi;
            #pragma unroll
            for (int r = 0; r < 4; r++) bjv[a][r] = (_Float16)bpt[gs][j0 + r];
        }
    }

    __syncthreads();

    // Weight register buffers, single-instance; reloaded right after last use
    // each super-chunk (wrap prefetches next step's sc=0 across the barrier).
    i64x2 Gp[4][2];     // g: 4 tiles x 2 subchunk-pairs
    i32x4 Q[12];        // ifo: 12 tiles
    #pragma unroll
    for (int pi = 0; pi < 4; pi++)
        #pragma unroll
        for (int h = 0; h < 2; h++)
            Gp[pi][h] = __builtin_bit_cast(i64x2, wqg[gbase + (pi * 2 + h) * 64]);
    #pragma unroll
    for (int t12 = 0; t12 < 12; t12++) Q[t12] = wq4[qbase + t12 * 64];

    #pragma unroll 1
    for (int t = 0; t < SEQL; t++) {
        const int rb = t & 1, wb = rb ^ 1;
        const char* hb8 = &h8s[rb][col * H8S];

        // Seed MFMA: acc = wx*x_t at per-gate scale (dominant term stays f16).
        f16x8 Bs = {};
        if (kq == 0) Bs[0] = (_Float16)x_s[col][t];
        f32x4 acc[16];
        #pragma unroll
        for (int a = 0; a < 16; a++) {
            f16x8 F = {};
            F[0] = __builtin_bit_cast(f16x2, sv2[a >> 1])[a & 1];
            acc[a] = __builtin_amdgcn_mfma_f32_16x16x32_f16(
                F, Bs, (f32x4){0.f, 0.f, 0.f, 0.f}, 0, 0, 0);
        }

        #pragma unroll
        for (int sc = 0; sc < 4; sc++) {
            const int scn = (sc + 1) & 3;
            // B operands from LDS (g: 4 x K=32 i64; ifo: one K=128 i32x8).
            const i64 Bm0 = *(const i64*)(hb8 + (4 * sc + 0) * 32 + kq * 8);
            const i64 Bm1 = *(const i64*)(hb8 + (4 * sc + 1) * 32 + kq * 8);
            const i64 Bm2 = *(const i64*)(hb8 + (4 * sc + 2) * 32 + kq * 8);
            const i64 Bm3 = *(const i64*)(hb8 + (4 * sc + 3) * 32 + kq * 8);
            const i32x8 Bv = ld_b32(hb8 + sc * 128 + kq * 32);
            // g MFMAs (fp8, K=32 x4), then reload Gp <- next super-chunk.
            #pragma unroll
            for (int pi = 0; pi < 4; pi++) {
                acc[pi] = mma8(Gp[pi][0].x, Bm0, acc[pi]);
                acc[pi] = mma8(Gp[pi][0].y, Bm1, acc[pi]);
                acc[pi] = mma8(Gp[pi][1].x, Bm2, acc[pi]);
                acc[pi] = mma8(Gp[pi][1].y, Bm3, acc[pi]);
            }
            #pragma unroll
            for (int pi = 0; pi < 4; pi++)
                #pragma unroll
                for (int h = 0; h < 2; h++)
                    Gp[pi][h] = __builtin_bit_cast(
                        i64x2, wqg[gbase + (scn * 8 + pi * 2 + h) * 64]);
            // ifo MFMAs (fp4, K=128), then reload Q <- next super-chunk.
            #pragma unroll
            for (int t12 = 0; t12 < 12; t12++)
                acc[4 + t12] = mma4(Q[t12], Bv, acc[4 + t12]);
            #pragma unroll
            for (int t12 = 0; t12 < 12; t12++)
                Q[t12] = wq4[qbase + scn * 768 + t12 * 64];
        }

        // Nonlinearity: g acc = preact*2^14, ifo acc = preact*2^17.
        const float S14 = 1.f / 16384.f, S17 = 1.f / 131072.f;
        #pragma unroll
        for (int pi = 0; pi < 4; pi++) {
            const int j0 = j00 + 128 * pi;
            float hr[4];
            #pragma unroll
            for (int r = 0; r < 4; r++) {
                const float g  = ftanh(fmaf(acc[pi][r],      S14, (float)bjv[pi][r]));
                const float ii = fsig (fmaf(acc[4 + pi][r],  S17, (float)bjv[4 + pi][r]));
                const float ff = fsig (fmaf(acc[8 + pi][r],  S17, (float)bjv[8 + pi][r]));
                const float oo = fsig (fmaf(acc[12 + pi][r], S17, (float)bjv[12 + pi][r]));
                const float cc = fmaf(g, ii, creg[pi][r] * ff);
                creg[pi][r] = cc;
                hr[r] = ftanh(cc) * oo;
            }
            int pk = __builtin_amdgcn_cvt_pk_fp8_f32(hr[0] * 128.f, hr[1] * 128.f, 0, false);
            pk     = __builtin_amdgcn_cvt_pk_fp8_f32(hr[2] * 128.f, hr[3] * 128.f, pk, true);
            *(unsigned*)&h8s[wb][col * H8S + j0] = (unsigned)pk;
            if (t == SEQL - 1) {
                f16x4 hv;
                #pragma unroll
                for (int r = 0; r < 4; r++) hv[r] = (_Float16)hr[r];
                *(f16x4*)&hfin[col][j0] = hv;
            }
        }
        __syncthreads();
    }

    // Epilogue: out[b][cls] = bp[cls] + sum_k wph[cls][k] * h_final[k][b]
    if (tid < NB * NCLS) {
        const int c = tid / NCLS, cls = tid - c * NCLS;
        float s = bp[cls];
        for (int k = 0; k < HID; k++)
            s = fmaf(wph[cls * HID + k], (float)hfin[c][k], s);
        out[(b0 + c) * NCLS + cls] = s;
    }
}

extern "C" void kernel_launch(void* const* d_in, const int* in_sizes, int n_in,
                              void* d_out, int out_size, void* d_ws, size_t ws_size,
                              hipStream_t stream)
{
    const float* x   = (const float*)d_in[0];
    const float* wgx = (const float*)d_in[1];
    const float* wix = (const float*)d_in[2];
    const float* wfx = (const float*)d_in[3];
    const float* wox = (const float*)d_in[4];
    const float* wgh = (const float*)d_in[5];
    const float* wih = (const float*)d_in[6];
    const float* wfh = (const float*)d_in[7];
    const float* woh = (const float*)d_in[8];
    const float* bg  = (const float*)d_in[9];
    const float* bi  = (const float*)d_in[10];
    const float* bf  = (const float*)d_in[11];
    const float* bo  = (const float*)d_in[12];
    const float* wph = (const float*)d_in[13];
    const float* bp  = (const float*)d_in[14];
    const float* h0  = (const float*)d_in[15];
    const float* c0  = (const float*)d_in[16];
    float* out = (float*)d_out;

    char* ws = (char*)d_ws;
    uint4* wqg = (uint4*)ws;                     // [0, 256K): g fp8 pair frags
    i32x4* wq4 = (i32x4*)(ws + (256u << 10));    // [256K, 640K): ifo fp4 frags

    pack_g  <<<dim3(64), dim3(256), 0, stream>>>(wgh, wqg);
    pack_ifo<<<dim3(96), dim3(256), 0, stream>>>(wih, wfh, woh, wq4);
    lstm_mfma<<<dim3(BATCH / NB), dim3(512), 0, stream>>>(
        x, wqg, wq4, wgx, wix, wfx, wox, bg, bi, bf, bo, wph, bp, h0, c0, out);
}

// Round 10
// 5580.915 us; speedup vs baseline: 1.5376x; 1.5376x over previous
//
#include <hip/hip_runtime.h>
#include <math.h>

#define HID   512
#define SEQL  256
#define BATCH 2048
#define NCLS  10
#define NB    16     // batch columns per WG = full MFMA tile width
#define H8S   544    // bytes per fp8 h row in LDS (512 used; 16B-mult)

typedef _Float16 f16x8 __attribute__((ext_vector_type(8)));
typedef _Float16 f16x4 __attribute__((ext_vector_type(4)));
typedef _Float16 f16x2 __attribute__((ext_vector_type(2)));
typedef float    f32x4 __attribute__((ext_vector_type(4)));
typedef int      i32x4 __attribute__((ext_vector_type(4)));
typedef int      i32x8 __attribute__((ext_vector_type(8)));
typedef long     i64;
typedef long     i64x2 __attribute__((ext_vector_type(2)));

__device__ __forceinline__ float fsig(float v)  { return 1.f / (1.f + __expf(-v)); }
__device__ __forceinline__ float ftanh(float v) { return 1.f - 2.f / (1.f + __expf(2.f * v)); }

// e2m1 nearest-round quantize of y (pre-scaled); grid {0,.5,1,1.5,2,3,4,6}.
__device__ __forceinline__ unsigned q4(float y) {
    const unsigned s = (y < 0.f) ? 8u : 0u;
    const float a = fabsf(y);
    const unsigned c = a < 0.25f ? 0u : a < 0.75f ? 1u : a < 1.25f ? 2u :
                       a < 1.75f ? 3u : a < 2.5f  ? 4u : a < 3.5f  ? 5u :
                       a < 5.0f  ? 6u : 7u;
    return s | c;
}

// ---- g-gate: fp8 chunk-pair fragments (R7 machinery, 1 gate) -------------
// wqg[(((wv*4+sc)*4+pi)*2+h)*64 + lane] : uint4 = A-frags for row-tile
// p = wv+8*pi, K=32 subchunks m0=4sc+2h (bytes 0-7), m1=m0+1 (bytes 8-15).
__global__ void pack_g(const float* __restrict__ wg, uint4* __restrict__ wqg)
{
    const int idx = blockIdx.x * 256 + threadIdx.x;   // 16384
    const int lane = idx & 63;
    const int h  = (idx >> 6) & 1;
    const int pi = (idx >> 7) & 3;
    const int sc = (idx >> 9) & 3;
    const int wv = idx >> 11;
    const int j = 16 * (wv + 8 * pi) + (lane & 15);
    unsigned dw[4];
    #pragma unroll
    for (int d = 0; d < 4; d++) {
        float f[4];
        #pragma unroll
        for (int e = 0; e < 4; e++) {
            const int v = 4 * d + e;
            const int k = (4 * sc + 2 * h + (v >> 3)) * 32 + (lane >> 4) * 8 + (v & 7);
            f[e] = wg[j * HID + k] * 128.f;
        }
        int pk = __builtin_amdgcn_cvt_pk_fp8_f32(f[0], f[1], 0, false);
        pk     = __builtin_amdgcn_cvt_pk_fp8_f32(f[2], f[3], pk, true);
        dw[d] = (unsigned)pk;
    }
    wqg[idx] = make_uint4(dw[0], dw[1], dw[2], dw[3]);
}

// ---- i/f/o: fp4 K=128 fragments (R8/R9 machinery, 3 gates) ---------------
// wq4[((wv*4+sc)*12 + t12)*64 + lane], t12 = gt*4+pi (gt: 0=i,1=f,2=o).
__global__ void pack_ifo(const float* __restrict__ wi, const float* __restrict__ wf,
                         const float* __restrict__ wo, i32x4* __restrict__ wq4)
{
    const int idx = blockIdx.x * 256 + threadIdx.x;   // 24576
    const int lane = idx & 63, blk = idx >> 6;
    const int t12 = blk % 12, r = blk / 12;
    const int sc = r & 3, wv = r >> 2;
    const int gt = t12 >> 2, pi = t12 & 3;
    const int j = 16 * (wv + 8 * pi) + (lane & 15);
    const int kbase = 128 * sc + (lane >> 4) * 32;
    const float* w = (gt == 0) ? wi : (gt == 1) ? wf : wo;
    int dw[4];
    #pragma unroll
    for (int d = 0; d < 4; d++) {
        unsigned u = 0;
        #pragma unroll
        for (int by = 0; by < 4; by++) {
            const int e0 = 8 * d + 2 * by;
            const unsigned c0 = q4(w[j * HID + kbase + e0]     * 1024.f);
            const unsigned c1 = q4(w[j * HID + kbase + e0 + 1] * 1024.f);
            u |= (c0 | (c1 << 4)) << (8 * by);
        }
        dw[d] = (int)u;
    }
    wq4[idx] = (i32x4){dw[0], dw[1], dw[2], dw[3]};
}

__device__ __forceinline__ f32x4 mma8(i64 a, i64 b, f32x4 c) {
    return __builtin_amdgcn_mfma_f32_16x16x32_fp8_fp8(a, b, c, 0, 0, 0);
}
// A fp4 (cbsz=4), B fp8 (blgp=0), neutral E8M0 scales.
__device__ __forceinline__ f32x4 mma4(i32x4 a, i32x8 b, f32x4 c) {
    const i32x8 av = __builtin_shufflevector(a, (i32x4){0, 0, 0, 0},
                                             0, 1, 2, 3, 4, 5, 6, 7);
    return __builtin_amdgcn_mfma_scale_f32_16x16x128_f8f6f4(
        av, b, c, 4, 0, 0, 0x7F7F7F7F, 0, 0x7F7F7F7F);
}
__device__ __forceinline__ i32x8 ld_b32(const char* p) {
    const i32x4 a = *(const i32x4*)p;
    const i32x4 b = *(const i32x4*)(p + 16);
    return __builtin_shufflevector(a, b, 0, 1, 2, 3, 4, 5, 6, 7);
}

// Persistent mixed-precision MFMA LSTM (R9 numerics + R7 register budget).
// R9 post-mortem: bjv(32) + oversized Gp(32) pushed per-wave demand past 256
// -> spill -> L2 thrash (WRITE 77MB, FETCH 10GB). This version: bias folded
// into the seed MFMA (Bs[1]=256, F[1]=b*scale/256), Gp single-buffer [4]
// reloaded twice per super-chunk (reload hides under the 12 ifo MFMAs).
// Weight buffers = 64 VGPR (R7 parity). 80 VMEM loads/wave/step.
__global__ __launch_bounds__(512, 1) void lstm_mfma(
    const float* __restrict__ x,                                   // [B][SEQ]
    const uint4* __restrict__ wqg, const i32x4* __restrict__ wq4,  // packed w
    const float* __restrict__ wgx, const float* __restrict__ wix,
    const float* __restrict__ wfx, const float* __restrict__ wox,  // [H]
    const float* __restrict__ bg,  const float* __restrict__ bi,
    const float* __restrict__ bf_, const float* __restrict__ bo,   // [H]
    const float* __restrict__ wph, const float* __restrict__ bp,   // [C][H], [C]
    const float* __restrict__ h_init, const float* __restrict__ c_init, // [H]
    float* __restrict__ out)                                       // [B][C]
{
    __shared__ __align__(16) char     h8s[2][NB * H8S];   // 17 KB fp8 h (x128)
    __shared__ float x_s[NB][SEQL + 1];                   // 16.4 KB
    __shared__ __align__(16) _Float16 hfin[NB][HID];      // 16 KB (final h only)

    const int tid  = threadIdx.x;
    const int lane = tid & 63;
    const int wv   = tid >> 6;
    const int col  = lane & 15;
    const int kq   = lane >> 4;
    const int b0   = blockIdx.x * NB;
    const int gbase = wv * 2048 + lane;   // uint4 units
    const int qbase = wv * 3072 + lane;   // i32x4 units

    for (int i = tid; i < NB * SEQL; i += 512)
        x_s[i >> 8][i & 255] = x[(b0 + (i >> 8)) * SEQL + (i & 255)];

    for (int i = tid; i < 2 * NB * H8S; i += 512) {
        const int b = i / (NB * H8S), k = (i % (NB * H8S)) % H8S;
        const float v = (b == 0 && k < HID) ? h_init[k] * 128.f : 0.f;
        const int pk = __builtin_amdgcn_cvt_pk_fp8_f32(v, 0.f, 0, false);
        ((char*)h8s)[i] = (char)(pk & 0xff);
    }

    const int j00 = 16 * wv + 4 * kq;     // + 128*pi per tile row-block
    f32x4 creg[4];
    #pragma unroll
    for (int pi = 0; pi < 4; pi++) creg[pi] = *(const f32x4*)&c_init[j00 + 128 * pi];

    // Seed A: acc a: 0-3 = g(pi), 4+t12 = ifo. F = {wx*sc, b*sc/256} f16x2;
    // with Bs = {x_t, 256} this yields acc = (wx*x + b) * sc. kq==0 lanes only.
    unsigned sv[16];
    {
        const float* gxp[4] = {wgx, wix, wfx, wox};
        const float* bpt[4] = {bg, bi, bf_, bo};
        #pragma unroll
        for (int a = 0; a < 16; a++) {
            const int pi = (a < 4) ? a : ((a - 4) & 3);
            const int gs = (a < 4) ? 0 : 1 + ((a - 4) >> 2);
            const int j  = 16 * (wv + 8 * pi) + col;
            const float sc  = (a < 4) ? 16384.f : 131072.f;
            f16x2 pr;
            pr[0] = (_Float16)(gxp[gs][j] * sc);
            pr[1] = (_Float16)(bpt[gs][j] * sc * (1.f / 256.f));
            sv[a] = (kq == 0) ? __builtin_bit_cast(unsigned, pr) : 0u;
        }
    }

    __syncthreads();

    // Weight register buffers: Gp[4] uint4 (16 VGPR), Q[12] i32x4 (48 VGPR).
    uint4 Gp[4];
    i32x4 Q[12];
    #pragma unroll
    for (int pi = 0; pi < 4; pi++) Gp[pi] = wqg[gbase + (pi * 2 + 0) * 64];
    #pragma unroll
    for (int t12 = 0; t12 < 12; t12++) Q[t12] = wq4[qbase + t12 * 64];

    #pragma unroll 1
    for (int t = 0; t < SEQL; t++) {
        const int rb = t & 1, wb = rb ^ 1;
        const char* hb8 = &h8s[rb][col * H8S];

        // Seed MFMA: acc = (wx*x_t + b) * per-gate scale.
        f16x8 Bs = {};
        if (kq == 0) { Bs[0] = (_Float16)x_s[col][t]; Bs[1] = (_Float16)256.f; }
        f32x4 acc[16];
        #pragma unroll
        for (int a = 0; a < 16; a++) {
            const f16x2 pr = __builtin_bit_cast(f16x2, sv[a]);
            f16x8 F = {};
            F[0] = pr[0]; F[1] = pr[1];
            acc[a] = __builtin_amdgcn_mfma_f32_16x16x32_f16(
                F, Bs, (f32x4){0.f, 0.f, 0.f, 0.f}, 0, 0, 0);
        }

        #pragma unroll
        for (int sc = 0; sc < 4; sc++) {
            const int scn = (sc + 1) & 3;
            // g half 0: subchunks 4sc+0, 4sc+1 (Gp holds (sc, h=0)).
            {
                const i64 Bm0 = *(const i64*)(hb8 + (4 * sc + 0) * 32 + kq * 8);
                const i64 Bm1 = *(const i64*)(hb8 + (4 * sc + 1) * 32 + kq * 8);
                #pragma unroll
                for (int pi = 0; pi < 4; pi++) {
                    const i64x2 gv = __builtin_bit_cast(i64x2, Gp[pi]);
                    acc[pi] = mma8(gv.x, Bm0, acc[pi]);
                    acc[pi] = mma8(gv.y, Bm1, acc[pi]);
                }
            }
            #pragma unroll
            for (int pi = 0; pi < 4; pi++)
                Gp[pi] = wqg[gbase + (sc * 8 + pi * 2 + 1) * 64];   // (sc, h=1)
            // ifo (fp4, K=128) — also hides the Gp reload above.
            {
                const i32x8 Bv = ld_b32(hb8 + sc * 128 + kq * 32);
                #pragma unroll
                for (int t12 = 0; t12 < 12; t12++)
                    acc[4 + t12] = mma4(Q[t12], Bv, acc[4 + t12]);
            }
            #pragma unroll
            for (int t12 = 0; t12 < 12; t12++)
                Q[t12] = wq4[qbase + scn * 768 + t12 * 64];         // next sc
            // g half 1: subchunks 4sc+2, 4sc+3 (Gp landed during ifo).
            {
                const i64 Bm2 = *(const i64*)(hb8 + (4 * sc + 2) * 32 + kq * 8);
                const i64 Bm3 = *(const i64*)(hb8 + (4 * sc + 3) * 32 + kq * 8);
                #pragma unroll
                for (int pi = 0; pi < 4; pi++) {
                    const i64x2 gv = __builtin_bit_cast(i64x2, Gp[pi]);
                    acc[pi] = mma8(gv.x, Bm2, acc[pi]);
                    acc[pi] = mma8(gv.y, Bm3, acc[pi]);
                }
            }
            #pragma unroll
            for (int pi = 0; pi < 4; pi++)
                Gp[pi] = wqg[gbase + (scn * 8 + pi * 2 + 0) * 64];  // (scn, h=0)
        }

        // Nonlinearity: g acc = preact*2^14, ifo acc = preact*2^17 (bias incl.)
        const float S14 = 1.f / 16384.f, S17 = 1.f / 131072.f;
        #pragma unroll
        for (int pi = 0; pi < 4; pi++) {
            const int j0 = j00 + 128 * pi;
            float hr[4];
            #pragma unroll
            for (int r = 0; r < 4; r++) {
                const float g  = ftanh(acc[pi][r]      * S14);
                const float ii = fsig (acc[4 + pi][r]  * S17);
                const float ff = fsig (acc[8 + pi][r]  * S17);
                const float oo = fsig (acc[12 + pi][r] * S17);
                const float cc = fmaf(g, ii, creg[pi][r] * ff);
                creg[pi][r] = cc;
                hr[r] = ftanh(cc) * oo;
            }
            int pk = __builtin_amdgcn_cvt_pk_fp8_f32(hr[0] * 128.f, hr[1] * 128.f, 0, false);
            pk     = __builtin_amdgcn_cvt_pk_fp8_f32(hr[2] * 128.f, hr[3] * 128.f, pk, true);
            *(unsigned*)&h8s[wb][col * H8S + j0] = (unsigned)pk;
            if (t == SEQL - 1) {
                f16x4 hv;
                #pragma unroll
                for (int r = 0; r < 4; r++) hv[r] = (_Float16)hr[r];
                *(f16x4*)&hfin[col][j0] = hv;
            }
        }
        __syncthreads();
    }

    // Epilogue: out[b][cls] = bp[cls] + sum_k wph[cls][k] * h_final[k][b]
    if (tid < NB * NCLS) {
        const int c = tid / NCLS, cls = tid - c * NCLS;
        float s = bp[cls];
        for (int k = 0; k < HID; k++)
            s = fmaf(wph[cls * HID + k], (float)hfin[c][k], s);
        out[(b0 + c) * NCLS + cls] = s;
    }
}

extern "C" void kernel_launch(void* const* d_in, const int* in_sizes, int n_in,
                              void* d_out, int out_size, void* d_ws, size_t ws_size,
                              hipStream_t stream)
{
    const float* x   = (const float*)d_in[0];
    const float* wgx = (const float*)d_in[1];
    const float* wix = (const float*)d_in[2];
    const float* wfx = (const float*)d_in[3];
    const float* wox = (const float*)d_in[4];
    const float* wgh = (const float*)d_in[5];
    const float* wih = (const float*)d_in[6];
    const float* wfh = (const float*)d_in[7];
    const float* woh = (const float*)d_in[8];
    const float* bg  = (const float*)d_in[9];
    const float* bi  = (const float*)d_in[10];
    const float* bf  = (const float*)d_in[11];
    const float* bo  = (const float*)d_in[12];
    const float* wph = (const float*)d_in[13];
    const float* bp  = (const float*)d_in[14];
    const float* h0  = (const float*)d_in[15];
    const float* c0  = (const float*)d_in[16];
    float* out = (float*)d_out;

    char* ws = (char*)d_ws;
    uint4* wqg = (uint4*)ws;                     // [0, 256K): g fp8 pair frags
    i32x4* wq4 = (i32x4*)(ws + (256u << 10));    // [256K, 640K): ifo fp4 frags

    pack_g  <<<dim3(64), dim3(256), 0, stream>>>(wgh, wqg);
    pack_ifo<<<dim3(96), dim3(256), 0, stream>>>(wih, wfh, woh, wq4);
    lstm_mfma<<<dim3(BATCH / NB), dim3(512), 0, stream>>>(
        x, wqg, wq4, wgx, wix, wfx, wox, bg, bi, bf, bo, wph, bp, h0, c0, out);
}

// Round 11
// 5573.454 us; speedup vs baseline: 1.5397x; 1.0013x over previous
//
#include <hip/hip_runtime.h>
#include <math.h>

#define HID   512
#define SEQL  256
#define BATCH 2048
#define NCLS  10
#define NB    16     // batch columns per WG = full MFMA tile width
#define H8S   552    // bytes per fp8 h row in LDS: 552/4 = 138 = 10 mod 32
                     // -> 16 cols hit 16 distinct banks (R7-proven, 458K confl);
                     // 544 (= 4 mod 32) gave 65M conflicts in R8-R10.

typedef _Float16 f16x8 __attribute__((ext_vector_type(8)));
typedef _Float16 f16x4 __attribute__((ext_vector_type(4)));
typedef _Float16 f16x2 __attribute__((ext_vector_type(2)));
typedef float    f32x4 __attribute__((ext_vector_type(4)));
typedef int      i32x4 __attribute__((ext_vector_type(4)));
typedef int      i32x8 __attribute__((ext_vector_type(8)));
typedef long     i64;
typedef long     i64x2 __attribute__((ext_vector_type(2)));

__device__ __forceinline__ float fsig(float v)  { return 1.f / (1.f + __expf(-v)); }
__device__ __forceinline__ float ftanh(float v) { return 1.f - 2.f / (1.f + __expf(2.f * v)); }

// e2m1 nearest-round quantize of y (pre-scaled); grid {0,.5,1,1.5,2,3,4,6}.
__device__ __forceinline__ unsigned q4(float y) {
    const unsigned s = (y < 0.f) ? 8u : 0u;
    const float a = fabsf(y);
    const unsigned c = a < 0.25f ? 0u : a < 0.75f ? 1u : a < 1.25f ? 2u :
                       a < 1.75f ? 3u : a < 2.5f  ? 4u : a < 3.5f  ? 5u :
                       a < 5.0f  ? 6u : 7u;
    return s | c;
}

// ---- g-gate: fp8 chunk-pair fragments (R7 machinery, 1 gate) -------------
// wqg[(((wv*4+sc)*4+pi)*2+h)*64 + lane] : uint4 = A-frags for row-tile
// p = wv+8*pi, K=32 subchunks m0=4sc+2h (bytes 0-7), m1=m0+1 (bytes 8-15).
__global__ void pack_g(const float* __restrict__ wg, uint4* __restrict__ wqg)
{
    const int idx = blockIdx.x * 256 + threadIdx.x;   // 16384
    const int lane = idx & 63;
    const int h  = (idx >> 6) & 1;
    const int pi = (idx >> 7) & 3;
    const int sc = (idx >> 9) & 3;
    const int wv = idx >> 11;
    const int j = 16 * (wv + 8 * pi) + (lane & 15);
    unsigned dw[4];
    #pragma unroll
    for (int d = 0; d < 4; d++) {
        float f[4];
        #pragma unroll
        for (int e = 0; e < 4; e++) {
            const int v = 4 * d + e;
            const int k = (4 * sc + 2 * h + (v >> 3)) * 32 + (lane >> 4) * 8 + (v & 7);
            f[e] = wg[j * HID + k] * 128.f;
        }
        int pk = __builtin_amdgcn_cvt_pk_fp8_f32(f[0], f[1], 0, false);
        pk     = __builtin_amdgcn_cvt_pk_fp8_f32(f[2], f[3], pk, true);
        dw[d] = (unsigned)pk;
    }
    wqg[idx] = make_uint4(dw[0], dw[1], dw[2], dw[3]);
}

// ---- i/f/o: fp4 K=128 fragments (R8/R9 machinery, 3 gates) ---------------
// wq4[((wv*4+sc)*12 + t12)*64 + lane], t12 = gt*4+pi (gt: 0=i,1=f,2=o).
__global__ void pack_ifo(const float* __restrict__ wi, const float* __restrict__ wf,
                         const float* __restrict__ wo, i32x4* __restrict__ wq4)
{
    const int idx = blockIdx.x * 256 + threadIdx.x;   // 24576
    const int lane = idx & 63, blk = idx >> 6;
    const int t12 = blk % 12, r = blk / 12;
    const int sc = r & 3, wv = r >> 2;
    const int gt = t12 >> 2, pi = t12 & 3;
    const int j = 16 * (wv + 8 * pi) + (lane & 15);
    const int kbase = 128 * sc + (lane >> 4) * 32;
    const float* w = (gt == 0) ? wi : (gt == 1) ? wf : wo;
    int dw[4];
    #pragma unroll
    for (int d = 0; d < 4; d++) {
        unsigned u = 0;
        #pragma unroll
        for (int by = 0; by < 4; by++) {
            const int e0 = 8 * d + 2 * by;
            const unsigned c0 = q4(w[j * HID + kbase + e0]     * 1024.f);
            const unsigned c1 = q4(w[j * HID + kbase + e0 + 1] * 1024.f);
            u |= (c0 | (c1 << 4)) << (8 * by);
        }
        dw[d] = (int)u;
    }
    wq4[idx] = (i32x4){dw[0], dw[1], dw[2], dw[3]};
}

__device__ __forceinline__ f32x4 mma8(i64 a, i64 b, f32x4 c) {
    return __builtin_amdgcn_mfma_f32_16x16x32_fp8_fp8(a, b, c, 0, 0, 0);
}
// A fp4 (cbsz=4), B fp8 (blgp=0), neutral E8M0 scales (x1.0).
__device__ __forceinline__ f32x4 mma4(i32x4 a, i32x8 b, f32x4 c) {
    const i32x8 av = __builtin_shufflevector(a, (i32x4){0, 0, 0, 0},
                                             0, 1, 2, 3, 4, 5, 6, 7);
    return __builtin_amdgcn_mfma_scale_f32_16x16x128_f8f6f4(
        av, b, c, 4, 0, 0, 0x7F7F7F7F, 0, 0x7F7F7F7F);
}
// 32-B fp8 B-operand from LDS as 4 x ds_read_b64 (8B-aligned at H8S=552;
// 2-way bank aliasing is free). Avoids the b128 16B-stride constraint.
__device__ __forceinline__ i32x8 ld_h128(const char* p) {
    union { i64 q[4]; i32x8 v; } u;
    u.q[0] = *(const i64*)(p);
    u.q[1] = *(const i64*)(p + 8);
    u.q[2] = *(const i64*)(p + 16);
    u.q[3] = *(const i64*)(p + 24);
    return u.v;
}

// Persistent mixed-precision MFMA LSTM (R9/R10 numerics, allocator-friendly).
// R10 post-mortem: Q[12] + 12-wide reload + mma4's 8-reg operand shadows
// overflowed the register file (WRITE 63MB spill, FETCH 8GB L2-thrash).
// This version caps live weights at Gp[4]+Qh[6] = 40 VGPR, each reloaded
// twice per super-chunk one block ahead. 80 VMEM loads/wave/step.
__global__ __launch_bounds__(512, 1) void lstm_mfma(
    const float* __restrict__ x,                                   // [B][SEQ]
    const uint4* __restrict__ wqg, const i32x4* __restrict__ wq4,  // packed w
    const float* __restrict__ wgx, const float* __restrict__ wix,
    const float* __restrict__ wfx, const float* __restrict__ wox,  // [H]
    const float* __restrict__ bg,  const float* __restrict__ bi,
    const float* __restrict__ bf_, const float* __restrict__ bo,   // [H]
    const float* __restrict__ wph, const float* __restrict__ bp,   // [C][H], [C]
    const float* __restrict__ h_init, const float* __restrict__ c_init, // [H]
    float* __restrict__ out)                                       // [B][C]
{
    __shared__ __align__(16) char     h8s[2][NB * H8S];   // 17.3 KB fp8 h (x128)
    __shared__ float x_s[NB][SEQL + 1];                   // 16.4 KB
    __shared__ __align__(16) _Float16 hfin[NB][HID];      // 16 KB (final h only)

    const int tid  = threadIdx.x;
    const int lane = tid & 63;
    const int wv   = tid >> 6;
    const int col  = lane & 15;
    const int kq   = lane >> 4;
    const int b0   = blockIdx.x * NB;
    const int gbase = wv * 2048 + lane;   // uint4 units
    const int qbase = wv * 3072 + lane;   // i32x4 units

    for (int i = tid; i < NB * SEQL; i += 512)
        x_s[i >> 8][i & 255] = x[(b0 + (i >> 8)) * SEQL + (i & 255)];

    for (int i = tid; i < 2 * NB * H8S; i += 512) {
        const int b = i / (NB * H8S), k = (i % (NB * H8S)) % H8S;
        const float v = (b == 0 && k < HID) ? h_init[k] * 128.f : 0.f;
        const int pk = __builtin_amdgcn_cvt_pk_fp8_f32(v, 0.f, 0, false);
        ((char*)h8s)[i] = (char)(pk & 0xff);
    }

    const int j00 = 16 * wv + 4 * kq;     // + 128*pi per tile row-block
    f32x4 creg[4];
    #pragma unroll
    for (int pi = 0; pi < 4; pi++) creg[pi] = *(const f32x4*)&c_init[j00 + 128 * pi];

    // Seed A: acc a: 0-3 = g(pi), 4+t12 = ifo. F = {wx*sc, b*sc/256} f16x2;
    // with Bs = {x_t, 256} this yields acc = (wx*x + b) * sc. kq==0 lanes only.
    unsigned sv[16];
    {
        const float* gxp[4] = {wgx, wix, wfx, wox};
        const float* bpt[4] = {bg, bi, bf_, bo};
        #pragma unroll
        for (int a = 0; a < 16; a++) {
            const int pi = (a < 4) ? a : ((a - 4) & 3);
            const int gs = (a < 4) ? 0 : 1 + ((a - 4) >> 2);
            const int j  = 16 * (wv + 8 * pi) + col;
            const float sc  = (a < 4) ? 16384.f : 131072.f;
            f16x2 pr;
            pr[0] = (_Float16)(gxp[gs][j] * sc);
            pr[1] = (_Float16)(bpt[gs][j] * sc * (1.f / 256.f));
            sv[a] = (kq == 0) ? __builtin_bit_cast(unsigned, pr) : 0u;
        }
    }

    __syncthreads();

    // Rolling weight buffers: Gp[4] uint4 (16 VGPR), Qh[6] i32x4 (24 VGPR).
    uint4 Gp[4];
    i32x4 Qh[6];
    #pragma unroll
    for (int pi = 0; pi < 4; pi++) Gp[pi] = wqg[gbase + (pi * 2 + 0) * 64];
    #pragma unroll
    for (int q6 = 0; q6 < 6; q6++) Qh[q6] = wq4[qbase + q6 * 64];

    #pragma unroll 1
    for (int t = 0; t < SEQL; t++) {
        const int rb = t & 1, wb = rb ^ 1;
        const char* hb8 = &h8s[rb][col * H8S];

        // Seed MFMA: acc = (wx*x_t + b) * per-gate scale.
        f16x8 Bs = {};
        if (kq == 0) { Bs[0] = (_Float16)x_s[col][t]; Bs[1] = (_Float16)256.f; }
        f32x4 acc[16];
        #pragma unroll
        for (int a = 0; a < 16; a++) {
            const f16x2 pr = __builtin_bit_cast(f16x2, sv[a]);
            f16x8 F = {};
            F[0] = pr[0]; F[1] = pr[1];
            acc[a] = __builtin_amdgcn_mfma_f32_16x16x32_f16(
                F, Bs, (f32x4){0.f, 0.f, 0.f, 0.f}, 0, 0, 0);
        }

        #pragma unroll
        for (int sc = 0; sc < 4; sc++) {
            const int scn = (sc + 1) & 3;
            // [1] g half 0: subchunks 4sc+0/1 (Gp holds (sc,h0)).
            {
                const i64 Bm0 = *(const i64*)(hb8 + (4 * sc + 0) * 32 + kq * 8);
                const i64 Bm1 = *(const i64*)(hb8 + (4 * sc + 1) * 32 + kq * 8);
                #pragma unroll
                for (int pi = 0; pi < 4; pi++) {
                    const i64x2 gv = __builtin_bit_cast(i64x2, Gp[pi]);
                    acc[pi] = mma8(gv.x, Bm0, acc[pi]);
                    acc[pi] = mma8(gv.y, Bm1, acc[pi]);
                }
            }
            // [2] Gp <- (sc, h1)
            #pragma unroll
            for (int pi = 0; pi < 4; pi++)
                Gp[pi] = wqg[gbase + (sc * 8 + pi * 2 + 1) * 64];
            // [3] ifo first half: t12 0..5 with K=128 B-operand.
            const i32x8 Bv = ld_h128(hb8 + sc * 128 + kq * 32);
            #pragma unroll
            for (int q6 = 0; q6 < 6; q6++)
                acc[4 + q6] = mma4(Qh[q6], Bv, acc[4 + q6]);
            // [4] Qh <- (sc) t12 6..11
            #pragma unroll
            for (int q6 = 0; q6 < 6; q6++)
                Qh[q6] = wq4[qbase + (sc * 12 + 6 + q6) * 64];
            // [5] g half 1: subchunks 4sc+2/3 (Gp landed during [3]).
            {
                const i64 Bm2 = *(const i64*)(hb8 + (4 * sc + 2) * 32 + kq * 8);
                const i64 Bm3 = *(const i64*)(hb8 + (4 * sc + 3) * 32 + kq * 8);
                #pragma unroll
                for (int pi = 0; pi < 4; pi++) {
                    const i64x2 gv = __builtin_bit_cast(i64x2, Gp[pi]);
                    acc[pi] = mma8(gv.x, Bm2, acc[pi]);
                    acc[pi] = mma8(gv.y, Bm3, acc[pi]);
                }
            }
            // [6] Gp <- (scn, h0)   (sc=3: next step's first g-group)
            #pragma unroll
            for (int pi = 0; pi < 4; pi++)
                Gp[pi] = wqg[gbase + (scn * 8 + pi * 2 + 0) * 64];
            // [7] ifo second half: t12 6..11 (Qh landed during [5]).
            #pragma unroll
            for (int q6 = 0; q6 < 6; q6++)
                acc[10 + q6] = mma4(Qh[q6], Bv, acc[10 + q6]);
            // [8] Qh <- (scn) t12 0..5  (sc=3: next step's first ifo-group)
            #pragma unroll
            for (int q6 = 0; q6 < 6; q6++)
                Qh[q6] = wq4[qbase + (scn * 12 + q6) * 64];
        }

        // Nonlinearity: g acc = preact*2^14, ifo acc = preact*2^17 (bias incl.)
        const float S14 = 1.f / 16384.f, S17 = 1.f / 131072.f;
        #pragma unroll
        for (int pi = 0; pi < 4; pi++) {
            const int j0 = j00 + 128 * pi;
            float hr[4];
            #pragma unroll
            for (int r = 0; r < 4; r++) {
                const float g  = ftanh(acc[pi][r]      * S14);
                const float ii = fsig (acc[4 + pi][r]  * S17);
                const float ff = fsig (acc[8 + pi][r]  * S17);
                const float oo = fsig (acc[12 + pi][r] * S17);
                const float cc = fmaf(g, ii, creg[pi][r] * ff);
                creg[pi][r] = cc;
                hr[r] = ftanh(cc) * oo;
            }
            int pk = __builtin_amdgcn_cvt_pk_fp8_f32(hr[0] * 128.f, hr[1] * 128.f, 0, false);
            pk     = __builtin_amdgcn_cvt_pk_fp8_f32(hr[2] * 128.f, hr[3] * 128.f, pk, true);
            *(unsigned*)&h8s[wb][col * H8S + j0] = (unsigned)pk;
            if (t == SEQL - 1) {
                f16x4 hv;
                #pragma unroll
                for (int r = 0; r < 4; r++) hv[r] = (_Float16)hr[r];
                *(f16x4*)&hfin[col][j0] = hv;
            }
        }
        __syncthreads();
    }

    // Epilogue: out[b][cls] = bp[cls] + sum_k wph[cls][k] * h_final[k][b]
    if (tid < NB * NCLS) {
        const int c = tid / NCLS, cls = tid - c * NCLS;
        float s = bp[cls];
        for (int k = 0; k < HID; k++)
            s = fmaf(wph[cls * HID + k], (float)hfin[c][k], s);
        out[(b0 + c) * NCLS + cls] = s;
    }
}

extern "C" void kernel_launch(void* const* d_in, const int* in_sizes, int n_in,
                              void* d_out, int out_size, void* d_ws, size_t ws_size,
                              hipStream_t stream)
{
    const float* x   = (const float*)d_in[0];
    const float* wgx = (const float*)d_in[1];
    const float* wix = (const float*)d_in[2];
    const float* wfx = (const float*)d_in[3];
    const float* wox = (const float*)d_in[4];
    const float* wgh = (const float*)d_in[5];
    const float* wih = (const float*)d_in[6];
    const float* wfh = (const float*)d_in[7];
    const float* woh = (const float*)d_in[8];
    const float* bg  = (const float*)d_in[9];
    const float* bi  = (const float*)d_in[10];
    const float* bf  = (const float*)d_in[11];
    const float* bo  = (const float*)d_in[12];
    const float* wph = (const float*)d_in[13];
    const float* bp  = (const float*)d_in[14];
    const float* h0  = (const float*)d_in[15];
    const float* c0  = (const float*)d_in[16];
    float* out = (float*)d_out;

    char* ws = (char*)d_ws;
    uint4* wqg = (uint4*)ws;                     // [0, 256K): g fp8 pair frags
    i32x4* wq4 = (i32x4*)(ws + (256u << 10));    // [256K, 640K): ifo fp4 frags

    pack_g  <<<dim3(64), dim3(256), 0, stream>>>(wgh, wqg);
    pack_ifo<<<dim3(96), dim3(256), 0, stream>>>(wih, wfh, woh, wq4);
    lstm_mfma<<<dim3(BATCH / NB), dim3(512), 0, stream>>>(
        x, wqg, wq4, wgx, wix, wfx, wox, bg, bi, bf, bo, wph, bp, h0, c0, out);
}

// Round 12
// 4773.343 us; speedup vs baseline: 1.7977x; 1.1676x over previous
//
#include <hip/hip_runtime.h>
#include <math.h>

#define HID   512
#define SEQL  256
#define BATCH 2048
#define NCLS  10
#define NB    16     // batch columns per WG = full MFMA tile width
#define H8S   552    // bytes per fp8 h row in LDS: 552/4 = 138 = 10 mod 32
                     // -> 16 cols hit 16 distinct banks (R7/R11-proven, 458K confl)

typedef _Float16 f16x8 __attribute__((ext_vector_type(8)));
typedef _Float16 f16x4 __attribute__((ext_vector_type(4)));
typedef _Float16 f16x2 __attribute__((ext_vector_type(2)));
typedef float    f32x4 __attribute__((ext_vector_type(4)));
typedef int      i32x4 __attribute__((ext_vector_type(4)));
typedef int      i32x8 __attribute__((ext_vector_type(8)));
typedef long     i64;
typedef long     i64x2 __attribute__((ext_vector_type(2)));

__device__ __forceinline__ float fsig(float v)  { return 1.f / (1.f + __expf(-v)); }
__device__ __forceinline__ float ftanh(float v) { return 1.f - 2.f / (1.f + __expf(2.f * v)); }

// e2m1 nearest-round quantize of y (pre-scaled); grid {0,.5,1,1.5,2,3,4,6}.
__device__ __forceinline__ unsigned q4(float y) {
    const unsigned s = (y < 0.f) ? 8u : 0u;
    const float a = fabsf(y);
    const unsigned c = a < 0.25f ? 0u : a < 0.75f ? 1u : a < 1.25f ? 2u :
                       a < 1.75f ? 3u : a < 2.5f  ? 4u : a < 3.5f  ? 5u :
                       a < 5.0f  ? 6u : 7u;
    return s | c;
}

// ---- g-gate: fp8 chunk-pair fragments (R7 machinery, 1 gate) -------------
// wqg[(((wv*4+sc)*4+pi)*2+h)*64 + lane] : uint4 = A-frags for row-tile
// p = wv+8*pi, K=32 subchunks m0=4sc+2h (bytes 0-7), m1=m0+1 (bytes 8-15).
__global__ void pack_g(const float* __restrict__ wg, uint4* __restrict__ wqg)
{
    const int idx = blockIdx.x * 256 + threadIdx.x;   // 16384
    const int lane = idx & 63;
    const int h  = (idx >> 6) & 1;
    const int pi = (idx >> 7) & 3;
    const int sc = (idx >> 9) & 3;
    const int wv = idx >> 11;
    const int j = 16 * (wv + 8 * pi) + (lane & 15);
    unsigned dw[4];
    #pragma unroll
    for (int d = 0; d < 4; d++) {
        float f[4];
        #pragma unroll
        for (int e = 0; e < 4; e++) {
            const int v = 4 * d + e;
            const int k = (4 * sc + 2 * h + (v >> 3)) * 32 + (lane >> 4) * 8 + (v & 7);
            f[e] = wg[j * HID + k] * 128.f;
        }
        int pk = __builtin_amdgcn_cvt_pk_fp8_f32(f[0], f[1], 0, false);
        pk     = __builtin_amdgcn_cvt_pk_fp8_f32(f[2], f[3], pk, true);
        dw[d] = (unsigned)pk;
    }
    wqg[idx] = make_uint4(dw[0], dw[1], dw[2], dw[3]);
}

// ---- i/f/o: fp4 K=128 fragments (R8/R9 machinery, 3 gates) ---------------
// wq4[((wv*4+sc)*12 + t12)*64 + lane], t12 = gt*4+pi (gt: 0=i,1=f,2=o).
__global__ void pack_ifo(const float* __restrict__ wi, const float* __restrict__ wf,
                         const float* __restrict__ wo, i32x4* __restrict__ wq4)
{
    const int idx = blockIdx.x * 256 + threadIdx.x;   // 24576
    const int lane = idx & 63, blk = idx >> 6;
    const int t12 = blk % 12, r = blk / 12;
    const int sc = r & 3, wv = r >> 2;
    const int gt = t12 >> 2, pi = t12 & 3;
    const int j = 16 * (wv + 8 * pi) + (lane & 15);
    const int kbase = 128 * sc + (lane >> 4) * 32;
    const float* w = (gt == 0) ? wi : (gt == 1) ? wf : wo;
    int dw[4];
    #pragma unroll
    for (int d = 0; d < 4; d++) {
        unsigned u = 0;
        #pragma unroll
        for (int by = 0; by < 4; by++) {
            const int e0 = 8 * d + 2 * by;
            const unsigned c0 = q4(w[j * HID + kbase + e0]     * 1024.f);
            const unsigned c1 = q4(w[j * HID + kbase + e0 + 1] * 1024.f);
            u |= (c0 | (c1 << 4)) << (8 * by);
        }
        dw[d] = (int)u;
    }
    wq4[idx] = (i32x4){dw[0], dw[1], dw[2], dw[3]};
}

__device__ __forceinline__ f32x4 mma8(i64 a, i64 b, f32x4 c) {
    return __builtin_amdgcn_mfma_f32_16x16x32_fp8_fp8(a, b, c, 0, 0, 0);
}
// A fp4 (cbsz=4), B fp8 (blgp=0), neutral E8M0 scales (x1.0).
__device__ __forceinline__ f32x4 mma4(i32x4 a, i32x8 b, f32x4 c) {
    const i32x8 av = __builtin_shufflevector(a, (i32x4){0, 0, 0, 0},
                                             0, 1, 2, 3, 4, 5, 6, 7);
    return __builtin_amdgcn_mfma_scale_f32_16x16x128_f8f6f4(
        av, b, c, 4, 0, 0, 0x7F7F7F7F, 0, 0x7F7F7F7F);
}
// 32-B fp8 B-operand from LDS as 4 x ds_read_b64 (8B-aligned at H8S=552;
// 2-way bank aliasing is free).
__device__ __forceinline__ i32x8 ld_h128(const char* p) {
    union { i64 q[4]; i32x8 v; } u;
    u.q[0] = *(const i64*)(p);
    u.q[1] = *(const i64*)(p + 8);
    u.q[2] = *(const i64*)(p + 16);
    u.q[3] = *(const i64*)(p + 24);
    return u.v;
}

// Persistent mixed-precision MFMA LSTM (R9 numerics; anti-LICM laundering).
// R10/R11 post-mortem: every weight address is t-invariant, so LLVM hoisted
// ~60 loads/lane out of the 256-step loop into SCRATCH (write-once 62.8MB,
// re-read 8GB/dispatch from HBM -> latency-bound). The fix: launder a zero
// offset through empty inline-asm each step so the addresses are unprovably
// invariant -> the 80 loads/wave/step stream from L2 as designed.
__global__ __launch_bounds__(512, 1) void lstm_mfma(
    const float* __restrict__ x,                                   // [B][SEQ]
    const uint4* __restrict__ wqg, const i32x4* __restrict__ wq4,  // packed w
    const float* __restrict__ wgx, const float* __restrict__ wix,
    const float* __restrict__ wfx, const float* __restrict__ wox,  // [H]
    const float* __restrict__ bg,  const float* __restrict__ bi,
    const float* __restrict__ bf_, const float* __restrict__ bo,   // [H]
    const float* __restrict__ wph, const float* __restrict__ bp,   // [C][H], [C]
    const float* __restrict__ h_init, const float* __restrict__ c_init, // [H]
    float* __restrict__ out)                                       // [B][C]
{
    __shared__ __align__(16) char     h8s[2][NB * H8S];   // 17.3 KB fp8 h (x128)
    __shared__ float x_s[NB][SEQL + 1];                   // 16.4 KB
    __shared__ __align__(16) _Float16 hfin[NB][HID];      // 16 KB (final h only)

    const int tid  = threadIdx.x;
    const int lane = tid & 63;
    const int wv   = tid >> 6;
    const int col  = lane & 15;
    const int kq   = lane >> 4;
    const int b0   = blockIdx.x * NB;
    const int gbase = wv * 2048 + lane;   // uint4 units
    const int qbase = wv * 3072 + lane;   // i32x4 units

    for (int i = tid; i < NB * SEQL; i += 512)
        x_s[i >> 8][i & 255] = x[(b0 + (i >> 8)) * SEQL + (i & 255)];

    for (int i = tid; i < 2 * NB * H8S; i += 512) {
        const int b = i / (NB * H8S), k = (i % (NB * H8S)) % H8S;
        const float v = (b == 0 && k < HID) ? h_init[k] * 128.f : 0.f;
        const int pk = __builtin_amdgcn_cvt_pk_fp8_f32(v, 0.f, 0, false);
        ((char*)h8s)[i] = (char)(pk & 0xff);
    }

    const int j00 = 16 * wv + 4 * kq;     // + 128*pi per tile row-block
    f32x4 creg[4];
    #pragma unroll
    for (int pi = 0; pi < 4; pi++) creg[pi] = *(const f32x4*)&c_init[j00 + 128 * pi];

    // Seed A: acc a: 0-3 = g(pi), 4+t12 = ifo. F = {wx*sc, b*sc/256} f16x2;
    // with Bs = {x_t, 256} this yields acc = (wx*x + b) * sc. kq==0 lanes only.
    unsigned sv[16];
    {
        const float* gxp[4] = {wgx, wix, wfx, wox};
        const float* bpt[4] = {bg, bi, bf_, bo};
        #pragma unroll
        for (int a = 0; a < 16; a++) {
            const int pi = (a < 4) ? a : ((a - 4) & 3);
            const int gs = (a < 4) ? 0 : 1 + ((a - 4) >> 2);
            const int j  = 16 * (wv + 8 * pi) + col;
            const float sc  = (a < 4) ? 16384.f : 131072.f;
            f16x2 pr;
            pr[0] = (_Float16)(gxp[gs][j] * sc);
            pr[1] = (_Float16)(bpt[gs][j] * sc * (1.f / 256.f));
            sv[a] = (kq == 0) ? __builtin_bit_cast(unsigned, pr) : 0u;
        }
    }

    __syncthreads();

    // Rolling weight buffers: Gp[4] uint4 (16 VGPR), Qh[6] i32x4 (24 VGPR).
    uint4 Gp[4];
    i32x4 Qh[6];
    #pragma unroll
    for (int pi = 0; pi < 4; pi++) Gp[pi] = wqg[gbase + (pi * 2 + 0) * 64];
    #pragma unroll
    for (int q6 = 0; q6 < 6; q6++) Qh[q6] = wq4[qbase + q6 * 64];

    int toff = 0;   // always 0, but unprovably so after laundering

    #pragma unroll 1
    for (int t = 0; t < SEQL; t++) {
        const int rb = t & 1, wb = rb ^ 1;
        const char* hb8 = &h8s[rb][col * H8S];

        // Anti-LICM: make weight addresses opaque for this iteration.
        asm volatile("" : "+v"(toff));
        const uint4* __restrict__ wqg_t = wqg + toff;
        const i32x4* __restrict__ wq4_t = wq4 + toff;

        // Seed MFMA: acc = (wx*x_t + b) * per-gate scale.
        f16x8 Bs = {};
        if (kq == 0) { Bs[0] = (_Float16)x_s[col][t]; Bs[1] = (_Float16)256.f; }
        f32x4 acc[16];
        #pragma unroll
        for (int a = 0; a < 16; a++) {
            const f16x2 pr = __builtin_bit_cast(f16x2, sv[a]);
            f16x8 F = {};
            F[0] = pr[0]; F[1] = pr[1];
            acc[a] = __builtin_amdgcn_mfma_f32_16x16x32_f16(
                F, Bs, (f32x4){0.f, 0.f, 0.f, 0.f}, 0, 0, 0);
        }

        #pragma unroll
        for (int sc = 0; sc < 4; sc++) {
            const int scn = (sc + 1) & 3;
            // [1] g half 0: subchunks 4sc+0/1 (Gp holds (sc,h0)).
            {
                const i64 Bm0 = *(const i64*)(hb8 + (4 * sc + 0) * 32 + kq * 8);
                const i64 Bm1 = *(const i64*)(hb8 + (4 * sc + 1) * 32 + kq * 8);
                #pragma unroll
                for (int pi = 0; pi < 4; pi++) {
                    const i64x2 gv = __builtin_bit_cast(i64x2, Gp[pi]);
                    acc[pi] = mma8(gv.x, Bm0, acc[pi]);
                    acc[pi] = mma8(gv.y, Bm1, acc[pi]);
                }
            }
            // [2] Gp <- (sc, h1)
            #pragma unroll
            for (int pi = 0; pi < 4; pi++)
                Gp[pi] = wqg_t[gbase + (sc * 8 + pi * 2 + 1) * 64];
            // [3] ifo first half: t12 0..5 with K=128 B-operand.
            const i32x8 Bv = ld_h128(hb8 + sc * 128 + kq * 32);
            #pragma unroll
            for (int q6 = 0; q6 < 6; q6++)
                acc[4 + q6] = mma4(Qh[q6], Bv, acc[4 + q6]);
            // [4] Qh <- (sc) t12 6..11
            #pragma unroll
            for (int q6 = 0; q6 < 6; q6++)
                Qh[q6] = wq4_t[qbase + (sc * 12 + 6 + q6) * 64];
            // [5] g half 1: subchunks 4sc+2/3 (Gp landed during [3]).
            {
                const i64 Bm2 = *(const i64*)(hb8 + (4 * sc + 2) * 32 + kq * 8);
                const i64 Bm3 = *(const i64*)(hb8 + (4 * sc + 3) * 32 + kq * 8);
                #pragma unroll
                for (int pi = 0; pi < 4; pi++) {
                    const i64x2 gv = __builtin_bit_cast(i64x2, Gp[pi]);
                    acc[pi] = mma8(gv.x, Bm2, acc[pi]);
                    acc[pi] = mma8(gv.y, Bm3, acc[pi]);
                }
            }
            // [6] Gp <- (scn, h0)   (sc=3: next step's first g-group)
            #pragma unroll
            for (int pi = 0; pi < 4; pi++)
                Gp[pi] = wqg_t[gbase + (scn * 8 + pi * 2 + 0) * 64];
            // [7] ifo second half: t12 6..11 (Qh landed during [5]).
            #pragma unroll
            for (int q6 = 0; q6 < 6; q6++)
                acc[10 + q6] = mma4(Qh[q6], Bv, acc[10 + q6]);
            // [8] Qh <- (scn) t12 0..5  (sc=3: next step's first ifo-group)
            #pragma unroll
            for (int q6 = 0; q6 < 6; q6++)
                Qh[q6] = wq4_t[qbase + (scn * 12 + q6) * 64];
        }

        // Nonlinearity: g acc = preact*2^14, ifo acc = preact*2^17 (bias incl.)
        const float S14 = 1.f / 16384.f, S17 = 1.f / 131072.f;
        #pragma unroll
        for (int pi = 0; pi < 4; pi++) {
            const int j0 = j00 + 128 * pi;
            float hr[4];
            #pragma unroll
            for (int r = 0; r < 4; r++) {
                const float g  = ftanh(acc[pi][r]      * S14);
                const float ii = fsig (acc[4 + pi][r]  * S17);
                const float ff = fsig (acc[8 + pi][r]  * S17);
                const float oo = fsig (acc[12 + pi][r] * S17);
                const float cc = fmaf(g, ii, creg[pi][r] * ff);
                creg[pi][r] = cc;
                hr[r] = ftanh(cc) * oo;
            }
            int pk = __builtin_amdgcn_cvt_pk_fp8_f32(hr[0] * 128.f, hr[1] * 128.f, 0, false);
            pk     = __builtin_amdgcn_cvt_pk_fp8_f32(hr[2] * 128.f, hr[3] * 128.f, pk, true);
            *(unsigned*)&h8s[wb][col * H8S + j0] = (unsigned)pk;
            if (t == SEQL - 1) {
                f16x4 hv;
                #pragma unroll
                for (int r = 0; r < 4; r++) hv[r] = (_Float16)hr[r];
                *(f16x4*)&hfin[col][j0] = hv;
            }
        }
        __syncthreads();
    }

    // Epilogue: out[b][cls] = bp[cls] + sum_k wph[cls][k] * h_final[k][b]
    if (tid < NB * NCLS) {
        const int c = tid / NCLS, cls = tid - c * NCLS;
        float s = bp[cls];
        for (int k = 0; k < HID; k++)
            s = fmaf(wph[cls * HID + k], (float)hfin[c][k], s);
        out[(b0 + c) * NCLS + cls] = s;
    }
}

extern "C" void kernel_launch(void* const* d_in, const int* in_sizes, int n_in,
                              void* d_out, int out_size, void* d_ws, size_t ws_size,
                              hipStream_t stream)
{
    const float* x   = (const float*)d_in[0];
    const float* wgx = (const float*)d_in[1];
    const float* wix = (const float*)d_in[2];
    const float* wfx = (const float*)d_in[3];
    const float* wox = (const float*)d_in[4];
    const float* wgh = (const float*)d_in[5];
    const float* wih = (const float*)d_in[6];
    const float* wfh = (const float*)d_in[7];
    const float* woh = (const float*)d_in[8];
    const float* bg  = (const float*)d_in[9];
    const float* bi  = (const float*)d_in[10];
    const float* bf  = (const float*)d_in[11];
    const float* bo  = (const float*)d_in[12];
    const float* wph = (const float*)d_in[13];
    const float* bp  = (const float*)d_in[14];
    const float* h0  = (const float*)d_in[15];
    const float* c0  = (const float*)d_in[16];
    float* out = (float*)d_out;

    char* ws = (char*)d_ws;
    uint4* wqg = (uint4*)ws;                     // [0, 256K): g fp8 pair frags
    i32x4* wq4 = (i32x4*)(ws + (256u << 10));    // [256K, 640K): ifo fp4 frags

    pack_g  <<<dim3(64), dim3(256), 0, stream>>>(wgh, wqg);
    pack_ifo<<<dim3(96), dim3(256), 0, stream>>>(wih, wfh, woh, wq4);
    lstm_mfma<<<dim3(BATCH / NB), dim3(512), 0, stream>>>(
        x, wqg, wq4, wgx, wix, wfx, wox, bg, bi, bf, bo, wph, bp, h0, c0, out);
}

// Round 13
// 4765.179 us; speedup vs baseline: 1.8008x; 1.0017x over previous
//
#include <hip/hip_runtime.h>
#include <math.h>

#define HID   512
#define SEQL  256
#define BATCH 2048
#define NCLS  10
#define NB    16     // batch columns per WG = full MFMA tile width
#define H8S   552    // bytes per fp8 h row in LDS: 552/4 = 138 = 10 mod 32
                     // -> 16 cols hit 16 distinct banks (R7/R11-proven, 458K confl)

typedef _Float16 f16x8 __attribute__((ext_vector_type(8)));
typedef _Float16 f16x4 __attribute__((ext_vector_type(4)));
typedef _Float16 f16x2 __attribute__((ext_vector_type(2)));
typedef float    f32x4 __attribute__((ext_vector_type(4)));
typedef int      i32x4 __attribute__((ext_vector_type(4)));
typedef int      i32x8 __attribute__((ext_vector_type(8)));
typedef long     i64;
typedef long     i64x2 __attribute__((ext_vector_type(2)));

__device__ __forceinline__ float fsig(float v)  { return 1.f / (1.f + __expf(-v)); }
__device__ __forceinline__ float ftanh(float v) { return 1.f - 2.f / (1.f + __expf(2.f * v)); }

// e2m1 nearest-round quantize of y (pre-scaled); grid {0,.5,1,1.5,2,3,4,6}.
__device__ __forceinline__ unsigned q4(float y) {
    const unsigned s = (y < 0.f) ? 8u : 0u;
    const float a = fabsf(y);
    const unsigned c = a < 0.25f ? 0u : a < 0.75f ? 1u : a < 1.25f ? 2u :
                       a < 1.75f ? 3u : a < 2.5f  ? 4u : a < 3.5f  ? 5u :
                       a < 5.0f  ? 6u : 7u;
    return s | c;
}

// ---- g-gate: fp8 chunk-pair fragments (R7 machinery, 1 gate) -------------
// wqg[(((wv*4+sc)*4+pi)*2+h)*64 + lane] : uint4 = A-frags for row-tile
// p = wv+8*pi, K=32 subchunks m0=4sc+2h (bytes 0-7), m1=m0+1 (bytes 8-15).
__global__ void pack_g(const float* __restrict__ wg, uint4* __restrict__ wqg)
{
    const int idx = blockIdx.x * 256 + threadIdx.x;   // 16384
    const int lane = idx & 63;
    const int h  = (idx >> 6) & 1;
    const int pi = (idx >> 7) & 3;
    const int sc = (idx >> 9) & 3;
    const int wv = idx >> 11;
    const int j = 16 * (wv + 8 * pi) + (lane & 15);
    unsigned dw[4];
    #pragma unroll
    for (int d = 0; d < 4; d++) {
        float f[4];
        #pragma unroll
        for (int e = 0; e < 4; e++) {
            const int v = 4 * d + e;
            const int k = (4 * sc + 2 * h + (v >> 3)) * 32 + (lane >> 4) * 8 + (v & 7);
            f[e] = wg[j * HID + k] * 128.f;
        }
        int pk = __builtin_amdgcn_cvt_pk_fp8_f32(f[0], f[1], 0, false);
        pk     = __builtin_amdgcn_cvt_pk_fp8_f32(f[2], f[3], pk, true);
        dw[d] = (unsigned)pk;
    }
    wqg[idx] = make_uint4(dw[0], dw[1], dw[2], dw[3]);
}

// ---- i/f/o: fp4 K=128 fragments (R8/R9 machinery, 3 gates) ---------------
// wq4[((wv*4+sc)*12 + t12)*64 + lane], t12 = gt*4+pi (gt: 0=i,1=f,2=o).
__global__ void pack_ifo(const float* __restrict__ wi, const float* __restrict__ wf,
                         const float* __restrict__ wo, i32x4* __restrict__ wq4)
{
    const int idx = blockIdx.x * 256 + threadIdx.x;   // 24576
    const int lane = idx & 63, blk = idx >> 6;
    const int t12 = blk % 12, r = blk / 12;
    const int sc = r & 3, wv = r >> 2;
    const int gt = t12 >> 2, pi = t12 & 3;
    const int j = 16 * (wv + 8 * pi) + (lane & 15);
    const int kbase = 128 * sc + (lane >> 4) * 32;
    const float* w = (gt == 0) ? wi : (gt == 1) ? wf : wo;
    int dw[4];
    #pragma unroll
    for (int d = 0; d < 4; d++) {
        unsigned u = 0;
        #pragma unroll
        for (int by = 0; by < 4; by++) {
            const int e0 = 8 * d + 2 * by;
            const unsigned c0 = q4(w[j * HID + kbase + e0]     * 1024.f);
            const unsigned c1 = q4(w[j * HID + kbase + e0 + 1] * 1024.f);
            u |= (c0 | (c1 << 4)) << (8 * by);
        }
        dw[d] = (int)u;
    }
    wq4[idx] = (i32x4){dw[0], dw[1], dw[2], dw[3]};
}

__device__ __forceinline__ f32x4 mma8(i64 a, i64 b, f32x4 c) {
    return __builtin_amdgcn_mfma_f32_16x16x32_fp8_fp8(a, b, c, 0, 0, 0);
}
// A fp4 (cbsz=4), B fp8 (blgp=0), neutral E8M0 scales (x1.0).
__device__ __forceinline__ f32x4 mma4(i32x4 a, i32x8 b, f32x4 c) {
    const i32x8 av = __builtin_shufflevector(a, (i32x4){0, 0, 0, 0},
                                             0, 1, 2, 3, 4, 5, 6, 7);
    return __builtin_amdgcn_mfma_scale_f32_16x16x128_f8f6f4(
        av, b, c, 4, 0, 0, 0x7F7F7F7F, 0, 0x7F7F7F7F);
}
// 32-B fp8 B-operand from LDS as 4 x ds_read_b64 (8B-aligned at H8S=552;
// 2-way bank aliasing is free).
__device__ __forceinline__ i32x8 ld_h128(const char* p) {
    union { i64 q[4]; i32x8 v; } u;
    u.q[0] = *(const i64*)(p);
    u.q[1] = *(const i64*)(p + 8);
    u.q[2] = *(const i64*)(p + 16);
    u.q[3] = *(const i64*)(p + 24);
    return u.v;
}

// Persistent mixed-precision MFMA LSTM (R12 + explicit register budget).
// R9-R12 post-mortem: backend budgeted 128 VGPR/wave (4-waves/EU heuristic);
// demand ~150+64acc -> forced in-loop spill (R12: WRITE 3.3GB, FETCH 2GB,
// VGPR pinned 128). TRUE occupancy is 1 WG x 8 waves/CU = 2 waves/EU, so
// the legal budget is 512/2 = 256 regs/wave. amdgpu_waves_per_eu(2) states
// that floor explicitly -> no spill. Single change vs R12.
__global__ __launch_bounds__(512)
__attribute__((amdgpu_waves_per_eu(2)))
void lstm_mfma(
    const float* __restrict__ x,                                   // [B][SEQ]
    const uint4* __restrict__ wqg, const i32x4* __restrict__ wq4,  // packed w
    const float* __restrict__ wgx, const float* __restrict__ wix,
    const float* __restrict__ wfx, const float* __restrict__ wox,  // [H]
    const float* __restrict__ bg,  const float* __restrict__ bi,
    const float* __restrict__ bf_, const float* __restrict__ bo,   // [H]
    const float* __restrict__ wph, const float* __restrict__ bp,   // [C][H], [C]
    const float* __restrict__ h_init, const float* __restrict__ c_init, // [H]
    float* __restrict__ out)                                       // [B][C]
{
    __shared__ __align__(16) char     h8s[2][NB * H8S];   // 17.3 KB fp8 h (x128)
    __shared__ float x_s[NB][SEQL + 1];                   // 16.4 KB
    __shared__ __align__(16) _Float16 hfin[NB][HID];      // 16 KB (final h only)

    const int tid  = threadIdx.x;
    const int lane = tid & 63;
    const int wv   = tid >> 6;
    const int col  = lane & 15;
    const int kq   = lane >> 4;
    const int b0   = blockIdx.x * NB;
    const int gbase = wv * 2048 + lane;   // uint4 units
    const int qbase = wv * 3072 + lane;   // i32x4 units

    for (int i = tid; i < NB * SEQL; i += 512)
        x_s[i >> 8][i & 255] = x[(b0 + (i >> 8)) * SEQL + (i & 255)];

    for (int i = tid; i < 2 * NB * H8S; i += 512) {
        const int b = i / (NB * H8S), k = (i % (NB * H8S)) % H8S;
        const float v = (b == 0 && k < HID) ? h_init[k] * 128.f : 0.f;
        const int pk = __builtin_amdgcn_cvt_pk_fp8_f32(v, 0.f, 0, false);
        ((char*)h8s)[i] = (char)(pk & 0xff);
    }

    const int j00 = 16 * wv + 4 * kq;     // + 128*pi per tile row-block
    f32x4 creg[4];
    #pragma unroll
    for (int pi = 0; pi < 4; pi++) creg[pi] = *(const f32x4*)&c_init[j00 + 128 * pi];

    // Seed A: acc a: 0-3 = g(pi), 4+t12 = ifo. F = {wx*sc, b*sc/256} f16x2;
    // with Bs = {x_t, 256} this yields acc = (wx*x + b) * sc. kq==0 lanes only.
    unsigned sv[16];
    {
        const float* gxp[4] = {wgx, wix, wfx, wox};
        const float* bpt[4] = {bg, bi, bf_, bo};
        #pragma unroll
        for (int a = 0; a < 16; a++) {
            const int pi = (a < 4) ? a : ((a - 4) & 3);
            const int gs = (a < 4) ? 0 : 1 + ((a - 4) >> 2);
            const int j  = 16 * (wv + 8 * pi) + col;
            const float sc  = (a < 4) ? 16384.f : 131072.f;
            f16x2 pr;
            pr[0] = (_Float16)(gxp[gs][j] * sc);
            pr[1] = (_Float16)(bpt[gs][j] * sc * (1.f / 256.f));
            sv[a] = (kq == 0) ? __builtin_bit_cast(unsigned, pr) : 0u;
        }
    }

    __syncthreads();

    // Rolling weight buffers: Gp[4] uint4 (16 VGPR), Qh[6] i32x4 (24 VGPR).
    uint4 Gp[4];
    i32x4 Qh[6];
    #pragma unroll
    for (int pi = 0; pi < 4; pi++) Gp[pi] = wqg[gbase + (pi * 2 + 0) * 64];
    #pragma unroll
    for (int q6 = 0; q6 < 6; q6++) Qh[q6] = wq4[qbase + q6 * 64];

    int toff = 0;   // always 0, but unprovably so after laundering

    #pragma unroll 1
    for (int t = 0; t < SEQL; t++) {
        const int rb = t & 1, wb = rb ^ 1;
        const char* hb8 = &h8s[rb][col * H8S];

        // Anti-LICM: make weight addresses opaque for this iteration.
        asm volatile("" : "+v"(toff));
        const uint4* __restrict__ wqg_t = wqg + toff;
        const i32x4* __restrict__ wq4_t = wq4 + toff;

        // Seed MFMA: acc = (wx*x_t + b) * per-gate scale.
        f16x8 Bs = {};
        if (kq == 0) { Bs[0] = (_Float16)x_s[col][t]; Bs[1] = (_Float16)256.f; }
        f32x4 acc[16];
        #pragma unroll
        for (int a = 0; a < 16; a++) {
            const f16x2 pr = __builtin_bit_cast(f16x2, sv[a]);
            f16x8 F = {};
            F[0] = pr[0]; F[1] = pr[1];
            acc[a] = __builtin_amdgcn_mfma_f32_16x16x32_f16(
                F, Bs, (f32x4){0.f, 0.f, 0.f, 0.f}, 0, 0, 0);
        }

        #pragma unroll
        for (int sc = 0; sc < 4; sc++) {
            const int scn = (sc + 1) & 3;
            // [1] g half 0: subchunks 4sc+0/1 (Gp holds (sc,h0)).
            {
                const i64 Bm0 = *(const i64*)(hb8 + (4 * sc + 0) * 32 + kq * 8);
                const i64 Bm1 = *(const i64*)(hb8 + (4 * sc + 1) * 32 + kq * 8);
                #pragma unroll
                for (int pi = 0; pi < 4; pi++) {
                    const i64x2 gv = __builtin_bit_cast(i64x2, Gp[pi]);
                    acc[pi] = mma8(gv.x, Bm0, acc[pi]);
                    acc[pi] = mma8(gv.y, Bm1, acc[pi]);
                }
            }
            // [2] Gp <- (sc, h1)
            #pragma unroll
            for (int pi = 0; pi < 4; pi++)
                Gp[pi] = wqg_t[gbase + (sc * 8 + pi * 2 + 1) * 64];
            // [3] ifo first half: t12 0..5 with K=128 B-operand.
            const i32x8 Bv = ld_h128(hb8 + sc * 128 + kq * 32);
            #pragma unroll
            for (int q6 = 0; q6 < 6; q6++)
                acc[4 + q6] = mma4(Qh[q6], Bv, acc[4 + q6]);
            // [4] Qh <- (sc) t12 6..11
            #pragma unroll
            for (int q6 = 0; q6 < 6; q6++)
                Qh[q6] = wq4_t[qbase + (sc * 12 + 6 + q6) * 64];
            // [5] g half 1: subchunks 4sc+2/3 (Gp landed during [3]).
            {
                const i64 Bm2 = *(const i64*)(hb8 + (4 * sc + 2) * 32 + kq * 8);
                const i64 Bm3 = *(const i64*)(hb8 + (4 * sc + 3) * 32 + kq * 8);
                #pragma unroll
                for (int pi = 0; pi < 4; pi++) {
                    const i64x2 gv = __builtin_bit_cast(i64x2, Gp[pi]);
                    acc[pi] = mma8(gv.x, Bm2, acc[pi]);
                    acc[pi] = mma8(gv.y, Bm3, acc[pi]);
                }
            }
            // [6] Gp <- (scn, h0)   (sc=3: next step's first g-group)
            #pragma unroll
            for (int pi = 0; pi < 4; pi++)
                Gp[pi] = wqg_t[gbase + (scn * 8 + pi * 2 + 0) * 64];
            // [7] ifo second half: t12 6..11 (Qh landed during [5]).
            #pragma unroll
            for (int q6 = 0; q6 < 6; q6++)
                acc[10 + q6] = mma4(Qh[q6], Bv, acc[10 + q6]);
            // [8] Qh <- (scn) t12 0..5  (sc=3: next step's first ifo-group)
            #pragma unroll
            for (int q6 = 0; q6 < 6; q6++)
                Qh[q6] = wq4_t[qbase + (scn * 12 + q6) * 64];
        }

        // Nonlinearity: g acc = preact*2^14, ifo acc = preact*2^17 (bias incl.)
        const float S14 = 1.f / 16384.f, S17 = 1.f / 131072.f;
        #pragma unroll
        for (int pi = 0; pi < 4; pi++) {
            const int j0 = j00 + 128 * pi;
            float hr[4];
            #pragma unroll
            for (int r = 0; r < 4; r++) {
                const float g  = ftanh(acc[pi][r]      * S14);
                const float ii = fsig (acc[4 + pi][r]  * S17);
                const float ff = fsig (acc[8 + pi][r]  * S17);
                const float oo = fsig (acc[12 + pi][r] * S17);
                const float cc = fmaf(g, ii, creg[pi][r] * ff);
                creg[pi][r] = cc;
                hr[r] = ftanh(cc) * oo;
            }
            int pk = __builtin_amdgcn_cvt_pk_fp8_f32(hr[0] * 128.f, hr[1] * 128.f, 0, false);
            pk     = __builtin_amdgcn_cvt_pk_fp8_f32(hr[2] * 128.f, hr[3] * 128.f, pk, true);
            *(unsigned*)&h8s[wb][col * H8S + j0] = (unsigned)pk;
            if (t == SEQL - 1) {
                f16x4 hv;
                #pragma unroll
                for (int r = 0; r < 4; r++) hv[r] = (_Float16)hr[r];
                *(f16x4*)&hfin[col][j0] = hv;
            }
        }
        __syncthreads();
    }

    // Epilogue: out[b][cls] = bp[cls] + sum_k wph[cls][k] * h_final[k][b]
    if (tid < NB * NCLS) {
        const int c = tid / NCLS, cls = tid - c * NCLS;
        float s = bp[cls];
        for (int k = 0; k < HID; k++)
            s = fmaf(wph[cls * HID + k], (float)hfin[c][k], s);
        out[(b0 + c) * NCLS + cls] = s;
    }
}

extern "C" void kernel_launch(void* const* d_in, const int* in_sizes, int n_in,
                              void* d_out, int out_size, void* d_ws, size_t ws_size,
                              hipStream_t stream)
{
    const float* x   = (const float*)d_in[0];
    const float* wgx = (const float*)d_in[1];
    const float* wix = (const float*)d_in[2];
    const float* wfx = (const float*)d_in[3];
    const float* wox = (const float*)d_in[4];
    const float* wgh = (const float*)d_in[5];
    const float* wih = (const float*)d_in[6];
    const float* wfh = (const float*)d_in[7];
    const float* woh = (const float*)d_in[8];
    const float* bg  = (const float*)d_in[9];
    const float* bi  = (const float*)d_in[10];
    const float* bf  = (const float*)d_in[11];
    const float* bo  = (const float*)d_in[12];
    const float* wph = (const float*)d_in[13];
    const float* bp  = (const float*)d_in[14];
    const float* h0  = (const float*)d_in[15];
    const float* c0  = (const float*)d_in[16];
    float* out = (float*)d_out;

    char* ws = (char*)d_ws;
    uint4* wqg = (uint4*)ws;                     // [0, 256K): g fp8 pair frags
    i32x4* wq4 = (i32x4*)(ws + (256u << 10));    // [256K, 640K): ifo fp4 frags

    pack_g  <<<dim3(64), dim3(256), 0, stream>>>(wgh, wqg);
    pack_ifo<<<dim3(96), dim3(256), 0, stream>>>(wih, wfh, woh, wq4);
    lstm_mfma<<<dim3(BATCH / NB), dim3(512), 0, stream>>>(
        x, wqg, wq4, wgx, wix, wfx, wox, bg, bi, bf, bo, wph, bp, h0, c0, out);
}

// Round 15
// 2340.473 us; speedup vs baseline: 3.6664x; 2.0360x over previous
//
#include <hip/hip_runtime.h>
#include <math.h>

#define HID   512
#define SEQL  256
#define BATCH 2048
#define NCLS  10
#define NB    16     // batch columns per WG = full MFMA tile width
#define H8S   552    // bytes per fp8 h row in LDS: 552/4 = 138 = 10 mod 32
                     // -> 16 cols hit 16 distinct banks (R7/R11-proven)

typedef _Float16 f16x8 __attribute__((ext_vector_type(8)));
typedef _Float16 f16x4 __attribute__((ext_vector_type(4)));
typedef _Float16 f16x2 __attribute__((ext_vector_type(2)));
typedef float    f32x4 __attribute__((ext_vector_type(4)));
typedef int      i32x4 __attribute__((ext_vector_type(4)));
typedef int      i32x8 __attribute__((ext_vector_type(8)));
typedef long     i64;
typedef long     i64x2 __attribute__((ext_vector_type(2)));

__device__ __forceinline__ float fsig(float v)  { return 1.f / (1.f + __expf(-v)); }
__device__ __forceinline__ float ftanh(float v) { return 1.f - 2.f / (1.f + __expf(2.f * v)); }

// e2m1 nearest-round quantize of y (pre-scaled); grid {0,.5,1,1.5,2,3,4,6}.
__device__ __forceinline__ unsigned q4(float y) {
    const unsigned s = (y < 0.f) ? 8u : 0u;
    const float a = fabsf(y);
    const unsigned c = a < 0.25f ? 0u : a < 0.75f ? 1u : a < 1.25f ? 2u :
                       a < 1.75f ? 3u : a < 2.5f  ? 4u : a < 3.5f  ? 5u :
                       a < 5.0f  ? 6u : 7u;
    return s | c;
}

// ---- g-gate: fp8 chunk-pair fragments (R7 machinery, 1 gate) -------------
// wqg[(((wv*4+sc)*4+pi)*2+h)*64 + lane] : uint4 = A-frags for row-tile
// p = wv+8*pi, K=32 subchunks m0=4sc+2h (bytes 0-7), m1=m0+1 (bytes 8-15).
__global__ void pack_g(const float* __restrict__ wg, uint4* __restrict__ wqg)
{
    const int idx = blockIdx.x * 256 + threadIdx.x;   // 16384
    const int lane = idx & 63;
    const int h  = (idx >> 6) & 1;
    const int pi = (idx >> 7) & 3;
    const int sc = (idx >> 9) & 3;
    const int wv = idx >> 11;
    const int j = 16 * (wv + 8 * pi) + (lane & 15);
    unsigned dw[4];
    #pragma unroll
    for (int d = 0; d < 4; d++) {
        float f[4];
        #pragma unroll
        for (int e = 0; e < 4; e++) {
            const int v = 4 * d + e;
            const int k = (4 * sc + 2 * h + (v >> 3)) * 32 + (lane >> 4) * 8 + (v & 7);
            f[e] = wg[j * HID + k] * 128.f;
        }
        int pk = __builtin_amdgcn_cvt_pk_fp8_f32(f[0], f[1], 0, false);
        pk     = __builtin_amdgcn_cvt_pk_fp8_f32(f[2], f[3], pk, true);
        dw[d] = (unsigned)pk;
    }
    wqg[idx] = make_uint4(dw[0], dw[1], dw[2], dw[3]);
}

// ---- i/f/o: fp4 K=128 fragments (R8/R9 machinery, 3 gates) ---------------
// wq4[((wv*4+sc)*12 + t12)*64 + lane], t12 = gt*4+pi (gt: 0=i,1=f,2=o).
__global__ void pack_ifo(const float* __restrict__ wi, const float* __restrict__ wf,
                         const float* __restrict__ wo, i32x4* __restrict__ wq4)
{
    const int idx = blockIdx.x * 256 + threadIdx.x;   // 24576
    const int lane = idx & 63, blk = idx >> 6;
    const int t12 = blk % 12, r = blk / 12;
    const int sc = r & 3, wv = r >> 2;
    const int gt = t12 >> 2, pi = t12 & 3;
    const int j = 16 * (wv + 8 * pi) + (lane & 15);
    const int kbase = 128 * sc + (lane >> 4) * 32;
    const float* w = (gt == 0) ? wi : (gt == 1) ? wf : wo;
    int dw[4];
    #pragma unroll
    for (int d = 0; d < 4; d++) {
        unsigned u = 0;
        #pragma unroll
        for (int by = 0; by < 4; by++) {
            const int e0 = 8 * d + 2 * by;
            const unsigned c0 = q4(w[j * HID + kbase + e0]     * 1024.f);
            const unsigned c1 = q4(w[j * HID + kbase + e0 + 1] * 1024.f);
            u |= (c0 | (c1 << 4)) << (8 * by);
        }
        dw[d] = (int)u;
    }
    wq4[idx] = (i32x4){dw[0], dw[1], dw[2], dw[3]};
}

// MFMA via inline asm with "+a" so C/D live in AGPRs. R9-R13 post-mortem:
// the _scale_ builtin kept acc[16] (64 regs) in arch VGPRs -> budget blown
// -> 49-dword/step scratch spill (WRITE 3.3GB). R7's plain-builtin kernel
// (acc in AGPR, VGPR=120, no spill) is the existence proof for this fix.
__device__ __forceinline__ void mma8a(f32x4& c, i64 a, i64 b) {
    asm volatile("v_mfma_f32_16x16x32_fp8_fp8 %0, %1, %2, %0"
                 : "+a"(c) : "v"(a), "v"(b));
}
// Non-scaled f8f6f4 MFMA (ISA §10): cbsz:4 = A fp4 -> A is a 4-REG tuple
// (R14 assembler: "wrong register tuple size for cbsz value 4" with 8 regs).
// B fp8 (blgp default 0) = 8-reg tuple. No shufflevector padding needed.
__device__ __forceinline__ void mma4a(f32x4& c, i32x4 a, i32x8 b) {
    asm volatile("v_mfma_f32_16x16x128_f8f6f4 %0, %1, %2, %0 cbsz:4"
                 : "+a"(c) : "v"(a), "v"(b));
}
// 32-B fp8 B-operand from LDS as 4 x ds_read_b64 (8B-aligned at H8S=552).
__device__ __forceinline__ i32x8 ld_h128(const char* p) {
    union { i64 q[4]; i32x8 v; } u;
    u.q[0] = *(const i64*)(p);
    u.q[1] = *(const i64*)(p + 8);
    u.q[2] = *(const i64*)(p + 16);
    u.q[3] = *(const i64*)(p + 24);
    return u.v;
}

// Persistent mixed-precision MFMA LSTM (R12 + AGPR-pinned accumulators).
__global__ __launch_bounds__(512, 1) void lstm_mfma(
    const float* __restrict__ x,                                   // [B][SEQ]
    const uint4* __restrict__ wqg, const i32x4* __restrict__ wq4,  // packed w
    const float* __restrict__ wgx, const float* __restrict__ wix,
    const float* __restrict__ wfx, const float* __restrict__ wox,  // [H]
    const float* __restrict__ bg,  const float* __restrict__ bi,
    const float* __restrict__ bf_, const float* __restrict__ bo,   // [H]
    const float* __restrict__ wph, const float* __restrict__ bp,   // [C][H], [C]
    const float* __restrict__ h_init, const float* __restrict__ c_init, // [H]
    float* __restrict__ out)                                       // [B][C]
{
    __shared__ __align__(16) char     h8s[2][NB * H8S];   // 17.3 KB fp8 h (x128)
    __shared__ float x_s[NB][SEQL + 1];                   // 16.4 KB
    __shared__ __align__(16) _Float16 hfin[NB][HID];      // 16 KB (final h only)

    const int tid  = threadIdx.x;
    const int lane = tid & 63;
    const int wv   = tid >> 6;
    const int col  = lane & 15;
    const int kq   = lane >> 4;
    const int b0   = blockIdx.x * NB;
    const int gbase = wv * 2048 + lane;   // uint4 units
    const int qbase = wv * 3072 + lane;   // i32x4 units

    for (int i = tid; i < NB * SEQL; i += 512)
        x_s[i >> 8][i & 255] = x[(b0 + (i >> 8)) * SEQL + (i & 255)];

    for (int i = tid; i < 2 * NB * H8S; i += 512) {
        const int b = i / (NB * H8S), k = (i % (NB * H8S)) % H8S;
        const float v = (b == 0 && k < HID) ? h_init[k] * 128.f : 0.f;
        const int pk = __builtin_amdgcn_cvt_pk_fp8_f32(v, 0.f, 0, false);
        ((char*)h8s)[i] = (char)(pk & 0xff);
    }

    const int j00 = 16 * wv + 4 * kq;     // + 128*pi per tile row-block
    f32x4 creg[4];
    #pragma unroll
    for (int pi = 0; pi < 4; pi++) creg[pi] = *(const f32x4*)&c_init[j00 + 128 * pi];

    // Seed A: acc a: 0-3 = g(pi), 4+t12 = ifo. F = {wx*sc, b*sc/256} f16x2;
    // with Bs = {x_t, 256} this yields acc = (wx*x + b) * sc. kq==0 lanes only.
    unsigned sv[16];
    {
        const float* gxp[4] = {wgx, wix, wfx, wox};
        const float* bpt[4] = {bg, bi, bf_, bo};
        #pragma unroll
        for (int a = 0; a < 16; a++) {
            const int pi = (a < 4) ? a : ((a - 4) & 3);
            const int gs = (a < 4) ? 0 : 1 + ((a - 4) >> 2);
            const int j  = 16 * (wv + 8 * pi) + col;
            const float sc  = (a < 4) ? 16384.f : 131072.f;
            f16x2 pr;
            pr[0] = (_Float16)(gxp[gs][j] * sc);
            pr[1] = (_Float16)(bpt[gs][j] * sc * (1.f / 256.f));
            sv[a] = (kq == 0) ? __builtin_bit_cast(unsigned, pr) : 0u;
        }
    }

    __syncthreads();

    // Rolling weight buffers: Gp[4] uint4 (16 VGPR), Qh[6] i32x4 (24 VGPR).
    uint4 Gp[4];
    i32x4 Qh[6];
    #pragma unroll
    for (int pi = 0; pi < 4; pi++) Gp[pi] = wqg[gbase + (pi * 2 + 0) * 64];
    #pragma unroll
    for (int q6 = 0; q6 < 6; q6++) Qh[q6] = wq4[qbase + q6 * 64];

    int toff = 0;   // always 0, but unprovably so after laundering

    #pragma unroll 1
    for (int t = 0; t < SEQL; t++) {
        const int rb = t & 1, wb = rb ^ 1;
        const char* hb8 = &h8s[rb][col * H8S];

        // Anti-LICM: make weight addresses opaque for this iteration.
        asm volatile("" : "+v"(toff));
        const uint4* __restrict__ wqg_t = wqg + toff;
        const i32x4* __restrict__ wq4_t = wq4 + toff;

        // Seed MFMA: acc = (wx*x_t + b) * per-gate scale.
        f16x8 Bs = {};
        if (kq == 0) { Bs[0] = (_Float16)x_s[col][t]; Bs[1] = (_Float16)256.f; }
        f32x4 acc[16];
        #pragma unroll
        for (int a = 0; a < 16; a++) {
            const f16x2 pr = __builtin_bit_cast(f16x2, sv[a]);
            f16x8 F = {};
            F[0] = pr[0]; F[1] = pr[1];
            acc[a] = __builtin_amdgcn_mfma_f32_16x16x32_f16(
                F, Bs, (f32x4){0.f, 0.f, 0.f, 0.f}, 0, 0, 0);
        }

        #pragma unroll
        for (int sc = 0; sc < 4; sc++) {
            const int scn = (sc + 1) & 3;
            // [1] g half 0: subchunks 4sc+0/1 (Gp holds (sc,h0)).
            {
                const i64 Bm0 = *(const i64*)(hb8 + (4 * sc + 0) * 32 + kq * 8);
                const i64 Bm1 = *(const i64*)(hb8 + (4 * sc + 1) * 32 + kq * 8);
                #pragma unroll
                for (int pi = 0; pi < 4; pi++) {
                    const i64x2 gv = __builtin_bit_cast(i64x2, Gp[pi]);
                    mma8a(acc[pi], gv.x, Bm0);
                    mma8a(acc[pi], gv.y, Bm1);
                }
            }
            // [2] Gp <- (sc, h1)
            #pragma unroll
            for (int pi = 0; pi < 4; pi++)
                Gp[pi] = wqg_t[gbase + (sc * 8 + pi * 2 + 1) * 64];
            // [3] ifo first half: t12 0..5 with K=128 B-operand.
            const i32x8 Bv = ld_h128(hb8 + sc * 128 + kq * 32);
            #pragma unroll
            for (int q6 = 0; q6 < 6; q6++)
                mma4a(acc[4 + q6], Qh[q6], Bv);
            // [4] Qh <- (sc) t12 6..11
            #pragma unroll
            for (int q6 = 0; q6 < 6; q6++)
                Qh[q6] = wq4_t[qbase + (sc * 12 + 6 + q6) * 64];
            // [5] g half 1: subchunks 4sc+2/3 (Gp landed during [3]).
            {
                const i64 Bm2 = *(const i64*)(hb8 + (4 * sc + 2) * 32 + kq * 8);
                const i64 Bm3 = *(const i64*)(hb8 + (4 * sc + 3) * 32 + kq * 8);
                #pragma unroll
                for (int pi = 0; pi < 4; pi++) {
                    const i64x2 gv = __builtin_bit_cast(i64x2, Gp[pi]);
                    mma8a(acc[pi], gv.x, Bm2);
                    mma8a(acc[pi], gv.y, Bm3);
                }
            }
            // [6] Gp <- (scn, h0)   (sc=3: next step's first g-group)
            #pragma unroll
            for (int pi = 0; pi < 4; pi++)
                Gp[pi] = wqg_t[gbase + (scn * 8 + pi * 2 + 0) * 64];
            // [7] ifo second half: t12 6..11 (Qh landed during [5]).
            #pragma unroll
            for (int q6 = 0; q6 < 6; q6++)
                mma4a(acc[10 + q6], Qh[q6], Bv);
            // [8] Qh <- (scn) t12 0..5  (sc=3: next step's first ifo-group)
            #pragma unroll
            for (int q6 = 0; q6 < 6; q6++)
                Qh[q6] = wq4_t[qbase + (scn * 12 + q6) * 64];
        }

        // MFMA->VALU read hazard fence: asm MFMAs are opaque to the hazard
        // recognizer; carry a data dep on the last-written accs + 16 nops.
        asm volatile("s_nop 7\n\ts_nop 7"
                     : "+a"(acc[12]), "+a"(acc[13]), "+a"(acc[14]), "+a"(acc[15]));

        // Nonlinearity: g acc = preact*2^14, ifo acc = preact*2^17 (bias incl.)
        const float S14 = 1.f / 16384.f, S17 = 1.f / 131072.f;
        #pragma unroll
        for (int pi = 0; pi < 4; pi++) {
            const int j0 = j00 + 128 * pi;
            float hr[4];
            #pragma unroll
            for (int r = 0; r < 4; r++) {
                const float g  = ftanh(acc[pi][r]      * S14);
                const float ii = fsig (acc[4 + pi][r]  * S17);
                const float ff = fsig (acc[8 + pi][r]  * S17);
                const float oo = fsig (acc[12 + pi][r] * S17);
                const float cc = fmaf(g, ii, creg[pi][r] * ff);
                creg[pi][r] = cc;
                hr[r] = ftanh(cc) * oo;
            }
            int pk = __builtin_amdgcn_cvt_pk_fp8_f32(hr[0] * 128.f, hr[1] * 128.f, 0, false);
            pk     = __builtin_amdgcn_cvt_pk_fp8_f32(hr[2] * 128.f, hr[3] * 128.f, pk, true);
            *(unsigned*)&h8s[wb][col * H8S + j0] = (unsigned)pk;
            if (t == SEQL - 1) {
                f16x4 hv;
                #pragma unroll
                for (int r = 0; r < 4; r++) hv[r] = (_Float16)hr[r];
                *(f16x4*)&hfin[col][j0] = hv;
            }
        }
        __syncthreads();
    }

    // Epilogue: out[b][cls] = bp[cls] + sum_k wph[cls][k] * h_final[k][b]
    if (tid < NB * NCLS) {
        const int c = tid / NCLS, cls = tid - c * NCLS;
        float s = bp[cls];
        for (int k = 0; k < HID; k++)
            s = fmaf(wph[cls * HID + k], (float)hfin[c][k], s);
        out[(b0 + c) * NCLS + cls] = s;
    }
}

extern "C" void kernel_launch(void* const* d_in, const int* in_sizes, int n_in,
                              void* d_out, int out_size, void* d_ws, size_t ws_size,
                              hipStream_t stream)
{
    const float* x   = (const float*)d_in[0];
    const float* wgx = (const float*)d_in[1];
    const float* wix = (const float*)d_in[2];
    const float* wfx = (const float*)d_in[3];
    const float* wox = (const float*)d_in[4];
    const float* wgh = (const float*)d_in[5];
    const float* wih = (const float*)d_in[6];
    const float* wfh = (const float*)d_in[7];
    const float* woh = (const float*)d_in[8];
    const float* bg  = (const float*)d_in[9];
    const float* bi  = (const float*)d_in[10];
    const float* bf  = (const float*)d_in[11];
    const float* bo  = (const float*)d_in[12];
    const float* wph = (const float*)d_in[13];
    const float* bp  = (const float*)d_in[14];
    const float* h0  = (const float*)d_in[15];
    const float* c0  = (const float*)d_in[16];
    float* out = (float*)d_out;

    char* ws = (char*)d_ws;
    uint4* wqg = (uint4*)ws;                     // [0, 256K): g fp8 pair frags
    i32x4* wq4 = (i32x4*)(ws + (256u << 10));    // [256K, 640K): ifo fp4 frags

    pack_g  <<<dim3(64), dim3(256), 0, stream>>>(wgh, wqg);
    pack_ifo<<<dim3(96), dim3(256), 0, stream>>>(wih, wfh, woh, wq4);
    lstm_mfma<<<dim3(BATCH / NB), dim3(512), 0, stream>>>(
        x, wqg, wq4, wgx, wix, wfx, wox, bg, bi, bf, bo, wph, bp, h0, c0, out);
}